// Round 4
// baseline (828.948 us; speedup 1.0000x reference)
//
#include <hip/hip_runtime.h>
#include <cstdint>

#define N_NODES 100000
#define N_EDGES 1600000
#define SCAN_NB 196   // ceil(100000/512)

typedef short bf16x8 __attribute__((ext_vector_type(8)));
typedef float f32x4 __attribute__((ext_vector_type(4)));
typedef float f32x2 __attribute__((ext_vector_type(2)));   // -> v_pk_fma_f32

// ---------- bf16 helpers ----------
__device__ __forceinline__ uint16_t f2bf(float f) {
    uint32_t b = __float_as_uint(f);
    return (uint16_t)((b + 0x7fffu + ((b >> 16) & 1u)) >> 16);  // RNE
}
__device__ __forceinline__ float bfval(uint16_t u) {
    return __uint_as_float(((uint32_t)u) << 16);
}
__device__ __forceinline__ float blo(uint32_t u) { return __uint_as_float(u << 16); }
__device__ __forceinline__ float bhi(uint32_t u) { return __uint_as_float(u & 0xffff0000u); }

__device__ __forceinline__ float fast_rcp(float x) { return __builtin_amdgcn_rcpf(x); }

// ---------- W1 pre-split to bf16 hi/lo (col-major: [col][k]) ----------
__global__ void cvt_w1(const float* __restrict__ W1, uint16_t* __restrict__ whi,
                       uint16_t* __restrict__ wlo) {
    int gid = blockIdx.x * 256 + threadIdx.x;   // 4096 threads
    int c = gid & 63, kg = gid >> 6;            // kg in [0,64): 8 k's each
    uint32_t dh[4], dl[4];
    #pragma unroll
    for (int t = 0; t < 4; ++t) {
        float v0 = W1[(kg * 8 + 2 * t) * 64 + c];
        float v1 = W1[(kg * 8 + 2 * t + 1) * 64 + c];
        uint16_t h0 = f2bf(v0), h1 = f2bf(v1);
        uint16_t l0 = f2bf(v0 - bfval(h0)), l1 = f2bf(v1 - bfval(h1));
        dh[t] = h0 | ((uint32_t)h1 << 16);
        dl[t] = l0 | ((uint32_t)l1 << 16);
    }
    *(uint4*)(whi + (long)c * 512 + kg * 8) = make_uint4(dh[0], dh[1], dh[2], dh[3]);
    *(uint4*)(wlo + (long)c * 512 + kg * 8) = make_uint4(dl[0], dl[1], dl[2], dl[3]);
}

// ---------- wl2[h][64] = W2 @ att_l2 per head (for al via associativity) ----------
__global__ __launch_bounds__(256) void wvec_k(const float* __restrict__ W2,
        const float* __restrict__ attl, const float* __restrict__ attr,
        float* __restrict__ wl2, float* __restrict__ wr2) {
    int t = blockIdx.x * 256 + threadIdx.x;   // 512 = (h, k)
    if (t >= 512) return;
    int h = t >> 6, k = t & 63;
    float sl = 0.f, sr = 0.f;
    #pragma unroll 8
    for (int c = 0; c < 40; ++c) {
        float w = W2[k * 320 + h * 40 + c];
        sl += w * attl[h * 40 + c];
        sr += w * attr[h * 40 + c];
    }
    wl2[t] = sl; wr2[t] = sr;
}

// ---------- Mcat[h] = W2_h @ W2_h^T (64x64 per head), split bf16 hi/lo,
//            stored col-major [kappa'=h*64+k'][k] for ygemm staging ----------
__global__ __launch_bounds__(512) void mcat_k(const float* __restrict__ W2,
        uint16_t* __restrict__ mhi, uint16_t* __restrict__ mlo) {
    __shared__ float Wh[64 * 40];
    int h = blockIdx.x;           // 8 blocks
    int tid = threadIdx.x;
    for (int t = tid; t < 2560; t += 512) {
        int k = t / 40, c = t % 40;
        Wh[k * 40 + c] = W2[k * 320 + h * 40 + c];
    }
    __syncthreads();
    #pragma unroll
    for (int r = 0; r < 8; ++r) {
        int o = r * 512 + tid;            // 4096 outputs (k', k)
        int kp = o >> 6, k = o & 63;
        float s = 0.f;
        #pragma unroll 8
        for (int c = 0; c < 40; ++c) s += Wh[k * 40 + c] * Wh[kp * 40 + c];
        uint16_t hi = f2bf(s);
        uint16_t lo = f2bf(s - bfval(hi));
        mhi[(h * 64 + kp) * 64 + k] = hi;
        mlo[(h * 64 + kp) * 64 + k] = lo;
    }
}

// ---------- W2L table for conv2 epilogue: [g:16][h:8][G:4][cc:10][s:4] bf16 ----------
__global__ __launch_bounds__(256) void w2l_k(const float* __restrict__ W2,
        uint16_t* __restrict__ w2lg) {
    int t = blockIdx.x * 256 + threadIdx.x;   // 20480
    if (t >= 20480) return;
    int s = t & 3, tmp = t >> 2;
    int cc = tmp % 10; tmp /= 10;
    int G = tmp & 3; tmp >>= 2;
    int h = tmp & 7; int g = tmp >> 3;
    w2lg[t] = f2bf(W2[(4 * g + s) * 320 + h * 40 + 10 * G + cc]);
}

// ---------- GEMM1 (split-bf16 MFMA): xw1[100000,64] = x @ W1, ~f32 accuracy ----------
__global__ __launch_bounds__(512) void gemm1_mfma(const float* __restrict__ x,
        const uint16_t* __restrict__ w1hi, const uint16_t* __restrict__ w1lo,
        float* __restrict__ xw1) {
    __shared__ __align__(16) char Ah[128 * 144];
    __shared__ __align__(16) char Al[128 * 144];
    __shared__ __align__(16) char Bh[64 * 144];
    __shared__ __align__(16) char Bl[64 * 144];
    int tid = threadIdx.x;
    int l = tid & 63, w = tid >> 6;
    long base = (long)blockIdx.x * 128;
    f32x4 acc[4];
    #pragma unroll
    for (int ct = 0; ct < 4; ++ct)
        #pragma unroll
        for (int j = 0; j < 4; ++j) acc[ct][j] = 0.f;

    for (int kb = 0; kb < 512; kb += 64) {
        __syncthreads();
        #pragma unroll
        for (int it = 0; it < 2; ++it) {
            int idx = tid + it * 512;
            int row = idx >> 3, kc = idx & 7;
            long r = base + row; if (r >= N_NODES) r = N_NODES - 1;
            const float4* p = (const float4*)(x + r * 512 + kb + kc * 8);
            float4 f0 = p[0], f1 = p[1];
            float v[8] = {f0.x, f0.y, f0.z, f0.w, f1.x, f1.y, f1.z, f1.w};
            uint32_t dh[4], dl[4];
            #pragma unroll
            for (int t = 0; t < 4; ++t) {
                uint16_t h0 = f2bf(v[2 * t]),     h1 = f2bf(v[2 * t + 1]);
                uint16_t l0 = f2bf(v[2 * t] - bfval(h0));
                uint16_t l1 = f2bf(v[2 * t + 1] - bfval(h1));
                dh[t] = h0 | ((uint32_t)h1 << 16);
                dl[t] = l0 | ((uint32_t)l1 << 16);
            }
            *(uint4*)(Ah + row * 144 + kc * 16) = make_uint4(dh[0], dh[1], dh[2], dh[3]);
            *(uint4*)(Al + row * 144 + kc * 16) = make_uint4(dl[0], dl[1], dl[2], dl[3]);
        }
        {
            int c = tid >> 3, kc = tid & 7;
            *(uint4*)(Bh + c * 144 + kc * 16) =
                *(const uint4*)(w1hi + (long)c * 512 + kb + kc * 8);
            *(uint4*)(Bl + c * 144 + kc * 16) =
                *(const uint4*)(w1lo + (long)c * 512 + kb + kc * 8);
        }
        __syncthreads();
        #pragma unroll
        for (int kk = 0; kk < 2; ++kk) {
            int aoff = (w * 16 + (l & 15)) * 144 + kk * 64 + (l >> 4) * 16;
            bf16x8 ah = *(const bf16x8*)(Ah + aoff);
            bf16x8 alo = *(const bf16x8*)(Al + aoff);
            #pragma unroll
            for (int ct = 0; ct < 4; ++ct) {
                int boff = (ct * 16 + (l & 15)) * 144 + kk * 64 + (l >> 4) * 16;
                bf16x8 bh = *(const bf16x8*)(Bh + boff);
                bf16x8 bl = *(const bf16x8*)(Bl + boff);
                acc[ct] = __builtin_amdgcn_mfma_f32_16x16x32_bf16(ah, bh, acc[ct], 0, 0, 0);
                acc[ct] = __builtin_amdgcn_mfma_f32_16x16x32_bf16(alo, bh, acc[ct], 0, 0, 0);
                acc[ct] = __builtin_amdgcn_mfma_f32_16x16x32_bf16(ah, bl, acc[ct], 0, 0, 0);
            }
        }
    }
    int nrow = w * 16 + (l >> 4) * 4;
    #pragma unroll
    for (int ct = 0; ct < 4; ++ct)
        #pragma unroll
        for (int j = 0; j < 4; ++j) {
            long node = base + nrow + j;
            if (node < N_NODES) xw1[node * 64 + ct * 16 + (l & 15)] = acc[ct][j];
        }
}

// ---------- YGEMM: Y[i][kappa'] = h_bf16 @ Mcat(split), written bf16 in
//            permuted layout [i][g:16][h:8][2 dwords] ----------
__global__ __launch_bounds__(512) void ygemm_mfma(const uint16_t* __restrict__ hjb,
        const uint16_t* __restrict__ mhi, const uint16_t* __restrict__ mlo,
        uint16_t* __restrict__ Y16) {
    __shared__ __align__(16) char Bh[256 * 144];
    __shared__ __align__(16) char Bl[256 * 144];
    int tid = threadIdx.x;
    int l = tid & 63, w = tid >> 6;
    int half = blockIdx.x & 1;
    long base = (long)(blockIdx.x >> 1) * 128;
    #pragma unroll
    for (int it = 0; it < 4; ++it) {
        int idx = tid + it * 512;
        int c = idx >> 3, kc = idx & 7;
        *(uint4*)(Bh + c * 144 + kc * 16) =
            *(const uint4*)(mhi + (long)(half * 256 + c) * 64 + kc * 8);
        *(uint4*)(Bl + c * 144 + kc * 16) =
            *(const uint4*)(mlo + (long)(half * 256 + c) * 64 + kc * 8);
    }
    long n0 = base + w * 16 + (l & 15);
    long nld = n0 < N_NODES ? n0 : N_NODES - 1;
    bf16x8 a[2];
    #pragma unroll
    for (int kk = 0; kk < 2; ++kk)
        a[kk] = *(const bf16x8*)(hjb + nld * 64 + kk * 32 + (l >> 4) * 8);
    __syncthreads();
    f32x4 acc[16];
    #pragma unroll
    for (int ct = 0; ct < 16; ++ct)
        #pragma unroll
        for (int j = 0; j < 4; ++j) acc[ct][j] = 0.f;
    #pragma unroll
    for (int ct = 0; ct < 16; ++ct) {
        #pragma unroll
        for (int kk = 0; kk < 2; ++kk) {
            bf16x8 bh = *(const bf16x8*)(Bh + (ct * 16 + (l & 15)) * 144 + kk * 64 + (l >> 4) * 16);
            bf16x8 bl = *(const bf16x8*)(Bl + (ct * 16 + (l & 15)) * 144 + kk * 64 + (l >> 4) * 16);
            acc[ct] = __builtin_amdgcn_mfma_f32_16x16x32_bf16(bh, a[kk], acc[ct], 0, 0, 0);
            acc[ct] = __builtin_amdgcn_mfma_f32_16x16x32_bf16(bl, a[kk], acc[ct], 0, 0, 0);
        }
    }
    if (n0 < N_NODES) {
        uint32_t* Yd = (uint32_t*)Y16;
        #pragma unroll
        for (int ct = 0; ct < 16; ++ct) {
            int kp = half * 256 + ct * 16 + (l >> 4) * 4;   // kappa' for j=0
            int k2 = kp & 63, hh = kp >> 6, gg = k2 >> 2;
            uint32_t d0 = f2bf(acc[ct][0]) | ((uint32_t)f2bf(acc[ct][1]) << 16);
            uint32_t d1 = f2bf(acc[ct][2]) | ((uint32_t)f2bf(acc[ct][3]) << 16);
            Yd[n0 * 256 + gg * 16 + hh * 2]     = d0;
            Yd[n0 * 256 + gg * 16 + hh * 2 + 1] = d1;
        }
    }
}

// ---------- CSR build (csr stores src*8) ----------
__global__ void hist_k(const int* __restrict__ dst, int* __restrict__ deg) {
    int e = blockIdx.x * blockDim.x + threadIdx.x;
    if (e < N_EDGES) atomicAdd(&deg[dst[e]], 1);
}

__global__ __launch_bounds__(512) void scan_a(const int* __restrict__ deg,
        int* __restrict__ offs, int* __restrict__ btot) {
    __shared__ int sh[512];
    int t = threadIdx.x;
    int g = blockIdx.x * 512 + t;
    int v = (g < N_NODES) ? deg[g] : 0;
    sh[t] = v;
    __syncthreads();
    #pragma unroll
    for (int o = 1; o < 512; o <<= 1) {
        int add = (t >= o) ? sh[t - o] : 0;
        __syncthreads();
        sh[t] += add;
        __syncthreads();
    }
    if (g < N_NODES) offs[g] = sh[t] - v;
    if (t == 511) btot[blockIdx.x] = sh[511];
}

__global__ __launch_bounds__(256) void scan_b(int* __restrict__ btot) {
    __shared__ int sh[256];
    int t = threadIdx.x;
    int v = (t < SCAN_NB) ? btot[t] : 0;
    sh[t] = v;
    __syncthreads();
    #pragma unroll
    for (int o = 1; o < 256; o <<= 1) {
        int add = (t >= o) ? sh[t - o] : 0;
        __syncthreads();
        sh[t] += add;
        __syncthreads();
    }
    if (t < SCAN_NB) btot[t] = sh[t] - v;
}

__global__ __launch_bounds__(512) void scan_c(int* __restrict__ offs,
        const int* __restrict__ btot, int* __restrict__ cursor) {
    int g = blockIdx.x * 512 + threadIdx.x;
    if (g < N_NODES) {
        int o = offs[g] + btot[blockIdx.x];
        offs[g] = o;
        cursor[g] = o;
    }
}

__global__ void scatter_k(const int* __restrict__ src, const int* __restrict__ dst,
        int* __restrict__ cursor, int* __restrict__ csr8) {
    int e = blockIdx.x * blockDim.x + threadIdx.x;
    if (e < N_EDGES) {
        int pos = atomicAdd(&cursor[dst[e]], 1);
        csr8[pos] = src[e] << 3;
    }
}

// ---------- conv1: head-per-lane, packed-f32 math; writes f32 hbuf + bf16 hjb ----------
__global__ __launch_bounds__(256) void conv1_node(const float* __restrict__ xw,
        const int* __restrict__ offs, const int* __restrict__ deg,
        const int* __restrict__ csr8, const float* __restrict__ att_l,
        const float* __restrict__ att_r, const float* __restrict__ b1,
        float* __restrict__ hout, uint16_t* __restrict__ hjb) {
    int wid = (blockIdx.x * blockDim.x + threadIdx.x) >> 6;
    if (wid >= N_NODES) return;
    int i = wid;
    int lane = threadIdx.x & 63;
    int g = lane >> 3, h = lane & 7;
    const float4* rowi = (const float4*)(xw + (long)i * 64 + h * 8);
    float4 xi0 = rowi[0], xi1 = rowi[1];
    f32x2 xip[4] = {{xi0.x, xi0.y}, {xi0.z, xi0.w}, {xi1.x, xi1.y}, {xi1.z, xi1.w}};
    const float4* alp4 = (const float4*)(att_l + h * 8);
    float4 t0 = alp4[0], t1 = alp4[1];
    f32x2 atlp[4] = {{t0.x, t0.y}, {t0.z, t0.w}, {t1.x, t1.y}, {t1.z, t1.w}};
    const float4* arp4 = (const float4*)(att_r + h * 8);
    float4 u0 = arp4[0], u1 = arp4[1];
    f32x2 atrp[4] = {{u0.x, u0.y}, {u0.z, u0.w}, {u1.x, u1.y}, {u1.z, u1.w}};
    f32x2 prp = xip[0] * atrp[0];
    prp += xip[1] * atrp[1];
    prp += xip[2] * atrp[2];
    prp += xip[3] * atrp[3];
    float pr = prp.x + prp.y;
    f32x2 accp[4] = {{0.f,0.f},{0.f,0.f},{0.f,0.f},{0.f,0.f}};
    float den = 0.f;

#define C1_EDGE(XJP) do { \
    f32x2 qdp = xip[0] * (XJP)[0]; \
    qdp += xip[1] * (XJP)[1]; \
    qdp += xip[2] * (XJP)[2]; \
    qdp += xip[3] * (XJP)[3]; \
    f32x2 qlp = (XJP)[0] * atlp[0]; \
    qlp += (XJP)[1] * atlp[1]; \
    qlp += (XJP)[2] * atlp[2]; \
    qlp += (XJP)[3] * atlp[3]; \
    float qd = qdp.x + qdp.y, ql = qlp.x + qlp.y; \
    float a = (ql + pr) * fast_rcp(1.0f + __expf(-qd)); \
    a = fmaxf(a, 0.2f * a); \
    float e = __expf(a); \
    den += e; \
    f32x2 ev = {e, e}; \
    accp[0] += ev * (XJP)[0]; \
    accp[1] += ev * (XJP)[1]; \
    accp[2] += ev * (XJP)[2]; \
    accp[3] += ev * (XJP)[3]; \
} while (0)

    if (g == 0) C1_EDGE(xip);   // self loop
    int off = offs[i], dg = deg[i];
    int k = g;
    for (; k + 8 < dg; k += 16) {
        int j0 = csr8[off + k], j1 = csr8[off + k + 8];
        const float4* r0 = (const float4*)(xw + (long)j0 * 8 + h * 8);
        const float4* r1 = (const float4*)(xw + (long)j1 * 8 + h * 8);
        float4 a0 = r0[0], a1 = r0[1];
        float4 b0 = r1[0], b1v = r1[1];
        f32x2 ap[4] = {{a0.x, a0.y}, {a0.z, a0.w}, {a1.x, a1.y}, {a1.z, a1.w}};
        f32x2 bp[4] = {{b0.x, b0.y}, {b0.z, b0.w}, {b1v.x, b1v.y}, {b1v.z, b1v.w}};
        C1_EDGE(ap);
        C1_EDGE(bp);
    }
    if (k < dg) {
        int j0 = csr8[off + k];
        const float4* r0 = (const float4*)(xw + (long)j0 * 8 + h * 8);
        float4 a0 = r0[0], a1 = r0[1];
        f32x2 ap[4] = {{a0.x, a0.y}, {a0.z, a0.w}, {a1.x, a1.y}, {a1.z, a1.w}};
        C1_EDGE(ap);
    }
#undef C1_EDGE

    float acc[8] = {accp[0].x, accp[0].y, accp[1].x, accp[1].y,
                    accp[2].x, accp[2].y, accp[3].x, accp[3].y};
    #pragma unroll
    for (int o = 8; o <= 32; o <<= 1) {
        #pragma unroll
        for (int t = 0; t < 8; ++t) acc[t] += __shfl_xor(acc[t], o);
        den += __shfl_xor(den, o);
    }
    if (g == 0) {
        float inv = fast_rcp(den + 1e-16f);
        const float4* bp4 = (const float4*)(b1 + h * 8);
        float4 c0 = bp4[0], c1 = bp4[1];
        float4 o0, o1;
        float v;
        v = acc[0]*inv + c0.x; o0.x = v > 0.f ? v : __expf(v) - 1.0f;
        v = acc[1]*inv + c0.y; o0.y = v > 0.f ? v : __expf(v) - 1.0f;
        v = acc[2]*inv + c0.z; o0.z = v > 0.f ? v : __expf(v) - 1.0f;
        v = acc[3]*inv + c0.w; o0.w = v > 0.f ? v : __expf(v) - 1.0f;
        v = acc[4]*inv + c1.x; o1.x = v > 0.f ? v : __expf(v) - 1.0f;
        v = acc[5]*inv + c1.y; o1.y = v > 0.f ? v : __expf(v) - 1.0f;
        v = acc[6]*inv + c1.z; o1.z = v > 0.f ? v : __expf(v) - 1.0f;
        v = acc[7]*inv + c1.w; o1.w = v > 0.f ? v : __expf(v) - 1.0f;
        float4* po = (float4*)(hout + (long)i * 64 + h * 8);
        po[0] = o0; po[1] = o1;
        uint32_t d0 = f2bf(o0.x) | ((uint32_t)f2bf(o0.y) << 16);
        uint32_t d1 = f2bf(o0.z) | ((uint32_t)f2bf(o0.w) << 16);
        uint32_t d2 = f2bf(o1.x) | ((uint32_t)f2bf(o1.y) << 16);
        uint32_t d3 = f2bf(o1.z) | ((uint32_t)f2bf(o1.w) << 16);
        *(uint4*)(hjb + (long)i * 64 + h * 8) = make_uint4(d0, d1, d2, d3);
    }
}

// ---------- al/ar from hbuf via precomputed wl2/wr2 (f32, accurate) ----------
__global__ __launch_bounds__(256) void node_att2h(const float* __restrict__ hbuf,
        const float* __restrict__ wl2, const float* __restrict__ wr2,
        float* __restrict__ al, float* __restrict__ ar) {
    __shared__ float lw[512], lr[512];
    int tid = threadIdx.x;
    for (int t = tid; t < 512; t += 256) { lw[t] = wl2[t]; lr[t] = wr2[t]; }
    __syncthreads();
    int i = blockIdx.x * 256 + tid;
    if (i >= N_NODES) return;
    const float4* row = (const float4*)(hbuf + (long)i * 64);
    float sl[8] = {0,0,0,0,0,0,0,0}, sr[8] = {0,0,0,0,0,0,0,0};
    #pragma unroll
    for (int d4 = 0; d4 < 16; ++d4) {
        float4 v = row[d4];
        #pragma unroll
        for (int hh = 0; hh < 8; ++hh) {
            const float4 wv = *(const float4*)(lw + hh * 64 + d4 * 4);
            const float4 rv = *(const float4*)(lr + hh * 64 + d4 * 4);
            sl[hh] += v.x*wv.x + v.y*wv.y + v.z*wv.z + v.w*wv.w;
            sr[hh] += v.x*rv.x + v.y*rv.y + v.z*rv.z + v.w*rv.w;
        }
    }
    #pragma unroll
    for (int hh = 0; hh < 8; ++hh) {
        al[i * 8 + hh] = sl[hh];
        ar[i * 8 + hh] = sr[hh];
    }
}

// ---------- conv2 (h-space): gather 128B bf16 h_j rows; logit = y_i . h_j;
//            aggregate in h-space; in-kernel epilogue agg@W2 + bias + lsm ----------
__global__ __launch_bounds__(256) void conv2_node(const uint16_t* __restrict__ hjb16,
        const int* __restrict__ offs, const int* __restrict__ deg,
        const int* __restrict__ csr8, const float* __restrict__ al,
        const float* __restrict__ ar, const uint16_t* __restrict__ Y16,
        const uint16_t* __restrict__ w2lg, const float* __restrict__ b2,
        float* __restrict__ out) {
    __shared__ __align__(16) uint16_t W2L[20480];  // 40 KB: [g][h][G][cc][s]
    for (int t = threadIdx.x; t < 2560; t += 256)
        ((uint4*)W2L)[t] = ((const uint4*)w2lg)[t];
    __syncthreads();
    if (blockIdx.x == 0 && threadIdx.x == 0) out[(long)N_NODES * 40] = 0.0f;  // att_loss
    int wid = (blockIdx.x * 256 + threadIdx.x) >> 6;
    if (wid >= N_NODES) return;
    int i = wid;
    int lane = threadIdx.x & 63;
    int g = lane & 15, G = lane >> 4, lam = lane & 7;
    const uint32_t* hjd = (const uint32_t*)hjb16;  // [N][32] dwords
    const uint32_t* Yd  = (const uint32_t*)Y16;    // [N][g:16][h:8][2] dwords

    // y_i: per lane m-indexed: y[m] covers head (lam^m), k-slice 4g..4g+3
    f32x2 y[8][2];
    #pragma unroll
    for (int m = 0; m < 8; ++m) {
        uint2 d = *(const uint2*)(Yd + (size_t)i * 256 + g * 16 + ((lam ^ m) * 2));
        y[m][0] = (f32x2){blo(d.x), bhi(d.x)};
        y[m][1] = (f32x2){blo(d.y), bhi(d.y)};
    }
    float ari = ar[i * 8 + lam];
    float b2v[10];
    #pragma unroll
    for (int cc = 0; cc < 10; ++cc) b2v[cc] = b2[10 * G + cc];

    f32x2 agg[8][2];
    #pragma unroll
    for (int m = 0; m < 8; ++m) { agg[m][0] = (f32x2){0.f,0.f}; agg[m][1] = (f32x2){0.f,0.f}; }
    float den = 0.f;
    int off = offs[i], dg = deg[i];

    auto CORE = [&](uint2 d, float alv, bool valid) {
        f32x2 h0 = {blo(d.x), bhi(d.x)}, h1 = {blo(d.y), bhi(d.y)};
        float pd[8];
        #pragma unroll
        for (int m = 0; m < 8; ++m) {
            f32x2 t = y[m][0] * h0;
            t += y[m][1] * h1;
            pd[m] = t.x + t.y;
        }
        // m-space split reduce over the 16-lane group (masks 4,2,1) + plain 8
        #pragma unroll
        for (int m = 0; m < 4; ++m) pd[m] += __shfl_xor(pd[m + 4], 4);
        pd[0] += __shfl_xor(pd[2], 2);
        pd[1] += __shfl_xor(pd[3], 2);
        pd[0] += __shfl_xor(pd[1], 1);
        pd[0] += __shfl_xor(pd[0], 8);
        // lane now holds full logit for head lam
        float a = (alv + ari) * fast_rcp(1.0f + __expf(-pd[0]));
        a = fmaxf(a, 0.2f * a);
        float e = __expf(a);
        e = valid ? e : 0.f;
        den += e;
        float f0 = e;
        float f[8]; f[0] = f0;
        #pragma unroll
        for (int m = 1; m < 8; ++m) f[m] = __shfl_xor(f0, m);  // head lam^m
        #pragma unroll
        for (int m = 0; m < 8; ++m) {
            f32x2 ev = {f[m], f[m]};
            agg[m][0] += ev * h0;
            agg[m][1] += ev * h1;
        }
    };

    // self loop (group 0 only)
    {
        uint2 ds = *(const uint2*)(hjd + (size_t)i * 32 + g * 2);
        float als = al[i * 8 + lam];
        CORE(ds, als, G == 0);
    }

    auto IDX = [&](int S) -> int {
        int e = G + 4 * S;
        int p = off + e;
        p = p < N_EDGES ? p : 0;
        int j = csr8[p];        // src*8
        return e < dg ? j : 0;
    };
    auto FETCH = [&](int j, uint2& d, float& a2) {
        d = *(const uint2*)(hjd + (size_t)j * 4 + g * 2);
        a2 = al[j + lam];
    };

    int nT = (dg + 3) >> 2;
    uint2 D0, D1; float A0v, A1v;
    {
        int j0 = IDX(0); FETCH(j0, D0, A0v);
        int j1 = IDX(1); FETCH(j1, D1, A1v);
    }
    int s = 0;
    while (s + 2 <= nT) {
        int j2 = IDX(s + 2);
        CORE(D0, A0v, G + 4 * s < dg);
        FETCH(j2, D0, A0v);
        int j3 = IDX(s + 3);
        CORE(D1, A1v, G + 4 * (s + 1) < dg);
        FETCH(j3, D1, A1v);
        s += 2;
    }
    if (s < nT)     CORE(D0, A0v, G + 4 * s < dg);
    if (s + 1 < nT) CORE(D1, A1v, G + 4 * (s + 1) < dg);

    // merge the 4 edge-groups (agg slices align: same g, same head map)
    #pragma unroll
    for (int m = 0; m < 8; ++m) {
        #pragma unroll
        for (int p = 0; p < 2; ++p) {
            f32x2 t16 = {__shfl_xor(agg[m][p].x, 16), __shfl_xor(agg[m][p].y, 16)};
            agg[m][p] += t16;
            f32x2 t32 = {__shfl_xor(agg[m][p].x, 32), __shfl_xor(agg[m][p].y, 32)};
            agg[m][p] += t32;
        }
    }
    den += __shfl_xor(den, 16);
    den += __shfl_xor(den, 32);
    // collect dens for all heads; scale agg by 1/(8*den_h)
    #pragma unroll
    for (int m = 0; m < 8; ++m) {
        float dm = (m == 0) ? den : __shfl_xor(den, m);
        float inv = 0.125f * fast_rcp(dm + 1e-16f);
        f32x2 iv = {inv, inv};
        agg[m][0] *= iv;
        agg[m][1] *= iv;
    }

    // epilogue: out[c=10G+cc] = sum_m sum_s agg[m][s] * W2[k=4g+s, h*40+c]
    f32x2 o2[10];
    #pragma unroll
    for (int cc = 0; cc < 10; ++cc) o2[cc] = (f32x2){0.f, 0.f};
    #pragma unroll
    for (int m = 0; m < 8; ++m) {
        const uint16_t* wp = W2L + (((g * 8 + (lam ^ m)) * 4 + G) * 40);
        uint4 wq0 = *(const uint4*)(wp);
        uint4 wq1 = *(const uint4*)(wp + 8);
        uint4 wq2 = *(const uint4*)(wp + 16);
        uint4 wq3 = *(const uint4*)(wp + 24);
        uint4 wq4 = *(const uint4*)(wp + 32);
        uint32_t wdw[20] = {wq0.x, wq0.y, wq0.z, wq0.w, wq1.x, wq1.y, wq1.z, wq1.w,
                            wq2.x, wq2.y, wq2.z, wq2.w, wq3.x, wq3.y, wq3.z, wq3.w,
                            wq4.x, wq4.y, wq4.z, wq4.w};
        #pragma unroll
        for (int cc = 0; cc < 10; ++cc) {
            f32x2 w0p = {blo(wdw[2 * cc]), bhi(wdw[2 * cc])};
            f32x2 w1p = {blo(wdw[2 * cc + 1]), bhi(wdw[2 * cc + 1])};
            o2[cc] += agg[m][0] * w0p;
            o2[cc] += agg[m][1] * w1p;
        }
    }
    float o[10];
    #pragma unroll
    for (int cc = 0; cc < 10; ++cc) o[cc] = o2[cc].x + o2[cc].y;
    // reduce partials over the 16 g-lanes
    #pragma unroll
    for (int r = 1; r <= 8; r <<= 1) {
        #pragma unroll
        for (int cc = 0; cc < 10; ++cc) o[cc] += __shfl_xor(o[cc], r);
    }
    #pragma unroll
    for (int cc = 0; cc < 10; ++cc) o[cc] += b2v[cc];
    // log_softmax over 40 (4 groups x 10)
    float mx = o[0];
    #pragma unroll
    for (int cc = 1; cc < 10; ++cc) mx = fmaxf(mx, o[cc]);
    mx = fmaxf(mx, __shfl_xor(mx, 16));
    mx = fmaxf(mx, __shfl_xor(mx, 32));
    float sm = 0.f;
    #pragma unroll
    for (int cc = 0; cc < 10; ++cc) sm += __expf(o[cc] - mx);
    sm += __shfl_xor(sm, 16);
    sm += __shfl_xor(sm, 32);
    float lse = mx + __logf(sm);
    if (g == 0) {
        float2* po = (float2*)(out + (long)i * 40 + 10 * G);
        #pragma unroll
        for (int t = 0; t < 5; ++t)
            po[t] = make_float2(o[2 * t] - lse, o[2 * t + 1] - lse);
    }
}

extern "C" void kernel_launch(void* const* d_in, const int* in_sizes, int n_in,
                              void* d_out, int out_size, void* d_ws, size_t ws_size,
                              hipStream_t stream) {
    const float* x      = (const float*)d_in[0];
    const int*   ei     = (const int*)d_in[1];
    const float* W1     = (const float*)d_in[2];
    const float* att_l1 = (const float*)d_in[3];
    const float* att_r1 = (const float*)d_in[4];
    const float* b1     = (const float*)d_in[5];
    const float* W2     = (const float*)d_in[6];
    const float* att_l2 = (const float*)d_in[7];
    const float* att_r2 = (const float*)d_in[8];
    const float* b2     = (const float*)d_in[9];
    const int* src = ei;
    const int* dst = ei + N_EDGES;
    float* out = (float*)d_out;

    char* ws = (char*)d_ws;
    // Y (102.4 MB) aliases xw1 (25.6) + hbuf (25.6): both dead before ygemm writes Y.
    uint16_t* Y      = (uint16_t*)(ws + 0);          // 102.4 MB
    float*    xw1    = (float*)(ws + 0);             // 25.6 MB (dead after conv1)
    float*    hbuf   = (float*)(ws + 25600000);      // 25.6 MB (dead after node_att2h)
    uint16_t* hjb    = (uint16_t*)(ws + 102400000);  // 12.8 MB (bf16 h rows)
    float*    al     = (float*)(ws + 115200000);     // 3.2 MB
    float*    ar     = (float*)(ws + 118400000);     // 3.2 MB
    int*      deg    = (int*)(ws + 121600000);       // 400 KB
    int*      offs   = (int*)(ws + 122000000);       // 400 KB
    int*      cursor = (int*)(ws + 122400000);       // 400 KB
    int*      btot   = (int*)(ws + 122800000);       // 1 KB
    int*      csr8   = (int*)(ws + 122801024);       // 6.4 MB
    uint16_t* w1hi   = (uint16_t*)(ws + 129201024);  // 64 KB
    uint16_t* w1lo   = (uint16_t*)(ws + 129266560);  // 64 KB
    uint16_t* mhi    = (uint16_t*)(ws + 129332096);  // 64 KB
    uint16_t* mlo    = (uint16_t*)(ws + 129397632);  // 64 KB
    uint16_t* w2lg   = (uint16_t*)(ws + 129463168);  // 40 KB
    float*    wl2    = (float*)(ws + 129504128);     // 2 KB
    float*    wr2    = (float*)(ws + 129506176);     // 2 KB -> ~129.5 MB total

    hipMemsetAsync(deg, 0, (size_t)N_NODES * 4, stream);

    // weight prep (independent of CSR)
    cvt_w1<<<16, 256, 0, stream>>>(W1, w1hi, w1lo);
    wvec_k<<<2, 256, 0, stream>>>(W2, att_l2, att_r2, wl2, wr2);
    mcat_k<<<8, 512, 0, stream>>>(W2, mhi, mlo);
    w2l_k<<<80, 256, 0, stream>>>(W2, w2lg);

    // CSR build (dst-sorted adjacency; csr stores src*8)
    hist_k<<<6250, 256, 0, stream>>>(dst, deg);
    scan_a<<<SCAN_NB, 512, 0, stream>>>(deg, offs, btot);
    scan_b<<<1, 256, 0, stream>>>(btot);
    scan_c<<<SCAN_NB, 512, 0, stream>>>(offs, btot, cursor);
    scatter_k<<<6250, 256, 0, stream>>>(src, dst, cursor, csr8);

    // conv1
    gemm1_mfma<<<782, 512, 0, stream>>>(x, w1hi, w1lo, xw1);
    conv1_node<<<25000, 256, 0, stream>>>(xw1, offs, deg, csr8, att_l1, att_r1, b1,
                                          hbuf, hjb);
    node_att2h<<<391, 256, 0, stream>>>(hbuf, wl2, wr2, al, ar);

    // Y = h @ Mcat (must run AFTER node_att2h: Y aliases hbuf/xw1)
    ygemm_mfma<<<1564, 512, 0, stream>>>(hjb, mhi, mlo, Y);

    // conv2 (h-space, fused epilogue + log_softmax)
    conv2_node<<<25000, 256, 0, stream>>>(hjb, offs, deg, csr8, al, ar, Y, w2lg, b2, out);
}

// Round 5
// 565.254 us; speedup vs baseline: 1.4665x; 1.4665x over previous
//
#include <hip/hip_runtime.h>
#include <cstdint>

#define N_NODES 100000
#define N_EDGES 1600000
#define SCAN_NB 196   // ceil(100000/512)

typedef short bf16x8 __attribute__((ext_vector_type(8)));
typedef float f32x4 __attribute__((ext_vector_type(4)));
typedef float f32x2 __attribute__((ext_vector_type(2)));   // -> v_pk_fma_f32

// ---------- bf16 helpers ----------
__device__ __forceinline__ uint16_t f2bf(float f) {
    uint32_t b = __float_as_uint(f);
    return (uint16_t)((b + 0x7fffu + ((b >> 16) & 1u)) >> 16);  // RNE
}
__device__ __forceinline__ float bfval(uint16_t u) {
    return __uint_as_float(((uint32_t)u) << 16);
}
__device__ __forceinline__ float blo(uint32_t u) { return __uint_as_float(u << 16); }
__device__ __forceinline__ float bhi(uint32_t u) { return __uint_as_float(u & 0xffff0000u); }

__device__ __forceinline__ float fast_rcp(float x) { return __builtin_amdgcn_rcpf(x); }

// ---------- W1 pre-split to bf16 hi/lo (col-major: [col][k]) ----------
__global__ void cvt_w1(const float* __restrict__ W1, uint16_t* __restrict__ whi,
                       uint16_t* __restrict__ wlo) {
    int gid = blockIdx.x * 256 + threadIdx.x;   // 4096 threads
    int c = gid & 63, kg = gid >> 6;            // kg in [0,64): 8 k's each
    uint32_t dh[4], dl[4];
    #pragma unroll
    for (int t = 0; t < 4; ++t) {
        float v0 = W1[(kg * 8 + 2 * t) * 64 + c];
        float v1 = W1[(kg * 8 + 2 * t + 1) * 64 + c];
        uint16_t h0 = f2bf(v0), h1 = f2bf(v1);
        uint16_t l0 = f2bf(v0 - bfval(h0)), l1 = f2bf(v1 - bfval(h1));
        dh[t] = h0 | ((uint32_t)h1 << 16);
        dl[t] = l0 | ((uint32_t)l1 << 16);
    }
    *(uint4*)(whi + (long)c * 512 + kg * 8) = make_uint4(dh[0], dh[1], dh[2], dh[3]);
    *(uint4*)(wlo + (long)c * 512 + kg * 8) = make_uint4(dl[0], dl[1], dl[2], dl[3]);
}

// ---------- wl2[h][64] = W2 @ att_l2 per head (for al via associativity) ----------
__global__ __launch_bounds__(256) void wvec_k(const float* __restrict__ W2,
        const float* __restrict__ attl, const float* __restrict__ attr,
        float* __restrict__ wl2, float* __restrict__ wr2) {
    int t = blockIdx.x * 256 + threadIdx.x;   // 512 = (h, k)
    if (t >= 512) return;
    int h = t >> 6, k = t & 63;
    float sl = 0.f, sr = 0.f;
    #pragma unroll 8
    for (int c = 0; c < 40; ++c) {
        float w = W2[k * 320 + h * 40 + c];
        sl += w * attl[h * 40 + c];
        sr += w * attr[h * 40 + c];
    }
    wl2[t] = sl; wr2[t] = sr;
}

// ---------- Mcat[h] = W2_h @ W2_h^T (64x64 per head), split bf16 hi/lo,
//            stored col-major [kappa'=h*64+k'][k] for ygemm staging ----------
__global__ __launch_bounds__(512) void mcat_k(const float* __restrict__ W2,
        uint16_t* __restrict__ mhi, uint16_t* __restrict__ mlo) {
    __shared__ float Wh[64 * 40];
    int h = blockIdx.x;           // 8 blocks
    int tid = threadIdx.x;
    for (int t = tid; t < 2560; t += 512) {
        int k = t / 40, c = t % 40;
        Wh[k * 40 + c] = W2[k * 320 + h * 40 + c];
    }
    __syncthreads();
    #pragma unroll
    for (int r = 0; r < 8; ++r) {
        int o = r * 512 + tid;            // 4096 outputs (k', k)
        int kp = o >> 6, k = o & 63;
        float s = 0.f;
        #pragma unroll 8
        for (int c = 0; c < 40; ++c) s += Wh[k * 40 + c] * Wh[kp * 40 + c];
        uint16_t hi = f2bf(s);
        uint16_t lo = f2bf(s - bfval(hi));
        mhi[(h * 64 + kp) * 64 + k] = hi;
        mlo[(h * 64 + kp) * 64 + k] = lo;
    }
}

// ---------- w2z: B[kappa=h*64+k][c] col-major [c:48][kappa:512] bf16 ----------
__global__ __launch_bounds__(256) void w2z_k(const float* __restrict__ W2,
        uint16_t* __restrict__ w2z) {
    int t = blockIdx.x * 256 + threadIdx.x;   // 48*512 = 24576
    if (t >= 24576) return;
    int c = t >> 9, kap = t & 511;
    int h = kap >> 6, k = kap & 63;
    float v = (c < 40) ? W2[k * 320 + h * 40 + c] : 0.f;
    w2z[c * 512 + kap] = f2bf(v);
}

// ---------- GEMM1 (split-bf16 MFMA): xw1 f32 + xw1b bf16 mirror ----------
__global__ __launch_bounds__(512) void gemm1_mfma(const float* __restrict__ x,
        const uint16_t* __restrict__ w1hi, const uint16_t* __restrict__ w1lo,
        float* __restrict__ xw1, uint16_t* __restrict__ xw1b) {
    __shared__ __align__(16) char Ah[128 * 144];
    __shared__ __align__(16) char Al[128 * 144];
    __shared__ __align__(16) char Bh[64 * 144];
    __shared__ __align__(16) char Bl[64 * 144];
    int tid = threadIdx.x;
    int l = tid & 63, w = tid >> 6;
    long base = (long)blockIdx.x * 128;
    f32x4 acc[4];
    #pragma unroll
    for (int ct = 0; ct < 4; ++ct)
        #pragma unroll
        for (int j = 0; j < 4; ++j) acc[ct][j] = 0.f;

    for (int kb = 0; kb < 512; kb += 64) {
        __syncthreads();
        #pragma unroll
        for (int it = 0; it < 2; ++it) {
            int idx = tid + it * 512;
            int row = idx >> 3, kc = idx & 7;
            long r = base + row; if (r >= N_NODES) r = N_NODES - 1;
            const float4* p = (const float4*)(x + r * 512 + kb + kc * 8);
            float4 f0 = p[0], f1 = p[1];
            float v[8] = {f0.x, f0.y, f0.z, f0.w, f1.x, f1.y, f1.z, f1.w};
            uint32_t dh[4], dl[4];
            #pragma unroll
            for (int t = 0; t < 4; ++t) {
                uint16_t h0 = f2bf(v[2 * t]),     h1 = f2bf(v[2 * t + 1]);
                uint16_t l0 = f2bf(v[2 * t] - bfval(h0));
                uint16_t l1 = f2bf(v[2 * t + 1] - bfval(h1));
                dh[t] = h0 | ((uint32_t)h1 << 16);
                dl[t] = l0 | ((uint32_t)l1 << 16);
            }
            *(uint4*)(Ah + row * 144 + kc * 16) = make_uint4(dh[0], dh[1], dh[2], dh[3]);
            *(uint4*)(Al + row * 144 + kc * 16) = make_uint4(dl[0], dl[1], dl[2], dl[3]);
        }
        {
            int c = tid >> 3, kc = tid & 7;
            *(uint4*)(Bh + c * 144 + kc * 16) =
                *(const uint4*)(w1hi + (long)c * 512 + kb + kc * 8);
            *(uint4*)(Bl + c * 144 + kc * 16) =
                *(const uint4*)(w1lo + (long)c * 512 + kb + kc * 8);
        }
        __syncthreads();
        #pragma unroll
        for (int kk = 0; kk < 2; ++kk) {
            int aoff = (w * 16 + (l & 15)) * 144 + kk * 64 + (l >> 4) * 16;
            bf16x8 ah = *(const bf16x8*)(Ah + aoff);
            bf16x8 alo = *(const bf16x8*)(Al + aoff);
            #pragma unroll
            for (int ct = 0; ct < 4; ++ct) {
                int boff = (ct * 16 + (l & 15)) * 144 + kk * 64 + (l >> 4) * 16;
                bf16x8 bh = *(const bf16x8*)(Bh + boff);
                bf16x8 bl = *(const bf16x8*)(Bl + boff);
                acc[ct] = __builtin_amdgcn_mfma_f32_16x16x32_bf16(ah, bh, acc[ct], 0, 0, 0);
                acc[ct] = __builtin_amdgcn_mfma_f32_16x16x32_bf16(alo, bh, acc[ct], 0, 0, 0);
                acc[ct] = __builtin_amdgcn_mfma_f32_16x16x32_bf16(ah, bl, acc[ct], 0, 0, 0);
            }
        }
    }
    int nrow = w * 16 + (l >> 4) * 4;
    #pragma unroll
    for (int ct = 0; ct < 4; ++ct)
        #pragma unroll
        for (int j = 0; j < 4; ++j) {
            long node = base + nrow + j;
            if (node < N_NODES) {
                int col = ct * 16 + (l & 15);
                xw1[node * 64 + col] = acc[ct][j];
                xw1b[node * 64 + col] = f2bf(acc[ct][j]);
            }
        }
}

// ---------- YGEMM: Y[i][kappa'] = h_bf16 @ Mcat(split), plain [i][kappa] bf16 ----------
__global__ __launch_bounds__(512) void ygemm_mfma(const uint16_t* __restrict__ hjb,
        const uint16_t* __restrict__ mhi, const uint16_t* __restrict__ mlo,
        uint16_t* __restrict__ Y16) {
    __shared__ __align__(16) char Bh[256 * 144];
    __shared__ __align__(16) char Bl[256 * 144];
    int tid = threadIdx.x;
    int l = tid & 63, w = tid >> 6;
    int half = blockIdx.x & 1;
    long base = (long)(blockIdx.x >> 1) * 128;
    #pragma unroll
    for (int it = 0; it < 4; ++it) {
        int idx = tid + it * 512;
        int c = idx >> 3, kc = idx & 7;
        *(uint4*)(Bh + c * 144 + kc * 16) =
            *(const uint4*)(mhi + (long)(half * 256 + c) * 64 + kc * 8);
        *(uint4*)(Bl + c * 144 + kc * 16) =
            *(const uint4*)(mlo + (long)(half * 256 + c) * 64 + kc * 8);
    }
    long n0 = base + w * 16 + (l & 15);
    long nld = n0 < N_NODES ? n0 : N_NODES - 1;
    bf16x8 a[2];
    #pragma unroll
    for (int kk = 0; kk < 2; ++kk)
        a[kk] = *(const bf16x8*)(hjb + nld * 64 + kk * 32 + (l >> 4) * 8);
    __syncthreads();
    f32x4 acc[16];
    #pragma unroll
    for (int ct = 0; ct < 16; ++ct)
        #pragma unroll
        for (int j = 0; j < 4; ++j) acc[ct][j] = 0.f;
    #pragma unroll
    for (int ct = 0; ct < 16; ++ct) {
        #pragma unroll
        for (int kk = 0; kk < 2; ++kk) {
            bf16x8 bh = *(const bf16x8*)(Bh + (ct * 16 + (l & 15)) * 144 + kk * 64 + (l >> 4) * 16);
            bf16x8 bl = *(const bf16x8*)(Bl + (ct * 16 + (l & 15)) * 144 + kk * 64 + (l >> 4) * 16);
            acc[ct] = __builtin_amdgcn_mfma_f32_16x16x32_bf16(bh, a[kk], acc[ct], 0, 0, 0);
            acc[ct] = __builtin_amdgcn_mfma_f32_16x16x32_bf16(bl, a[kk], acc[ct], 0, 0, 0);
        }
    }
    if (n0 < N_NODES) {
        uint32_t* Yd = (uint32_t*)Y16;
        #pragma unroll
        for (int ct = 0; ct < 16; ++ct) {
            int kp = half * 256 + ct * 16 + (l >> 4) * 4;   // kappa' of acc[ct][0]
            uint32_t d0 = f2bf(acc[ct][0]) | ((uint32_t)f2bf(acc[ct][1]) << 16);
            uint32_t d1 = f2bf(acc[ct][2]) | ((uint32_t)f2bf(acc[ct][3]) << 16);
            Yd[n0 * 256 + (kp >> 1)]     = d0;
            Yd[n0 * 256 + (kp >> 1) + 1] = d1;
        }
    }
}

// ---------- CSR build (csr stores src*8) ----------
__global__ void hist_k(const int* __restrict__ dst, int* __restrict__ deg) {
    int e = blockIdx.x * blockDim.x + threadIdx.x;
    if (e < N_EDGES) atomicAdd(&deg[dst[e]], 1);
}

__global__ __launch_bounds__(512) void scan_a(const int* __restrict__ deg,
        int* __restrict__ offs, int* __restrict__ btot) {
    __shared__ int sh[512];
    int t = threadIdx.x;
    int g = blockIdx.x * 512 + t;
    int v = (g < N_NODES) ? deg[g] : 0;
    sh[t] = v;
    __syncthreads();
    #pragma unroll
    for (int o = 1; o < 512; o <<= 1) {
        int add = (t >= o) ? sh[t - o] : 0;
        __syncthreads();
        sh[t] += add;
        __syncthreads();
    }
    if (g < N_NODES) offs[g] = sh[t] - v;
    if (t == 511) btot[blockIdx.x] = sh[511];
}

__global__ __launch_bounds__(256) void scan_b(int* __restrict__ btot) {
    __shared__ int sh[256];
    int t = threadIdx.x;
    int v = (t < SCAN_NB) ? btot[t] : 0;
    sh[t] = v;
    __syncthreads();
    #pragma unroll
    for (int o = 1; o < 256; o <<= 1) {
        int add = (t >= o) ? sh[t - o] : 0;
        __syncthreads();
        sh[t] += add;
        __syncthreads();
    }
    if (t < SCAN_NB) btot[t] = sh[t] - v;
}

__global__ __launch_bounds__(512) void scan_c(int* __restrict__ offs,
        const int* __restrict__ btot, int* __restrict__ cursor) {
    int g = blockIdx.x * 512 + threadIdx.x;
    if (g < N_NODES) {
        int o = offs[g] + btot[blockIdx.x];
        offs[g] = o;
        cursor[g] = o;
    }
}

__global__ void scatter_k(const int* __restrict__ src, const int* __restrict__ dst,
        int* __restrict__ cursor, int* __restrict__ csr8) {
    int e = blockIdx.x * blockDim.x + threadIdx.x;
    if (e < N_EDGES) {
        int pos = atomicAdd(&cursor[dst[e]], 1);
        csr8[pos] = src[e] << 3;
    }
}

// ---------- conv1: head-per-lane; bf16 gathers from xw1b, f32 center row ----------
__global__ __launch_bounds__(256) void conv1_node(const float* __restrict__ xw,
        const uint16_t* __restrict__ xwb,
        const int* __restrict__ offs, const int* __restrict__ deg,
        const int* __restrict__ csr8, const float* __restrict__ att_l,
        const float* __restrict__ att_r, const float* __restrict__ b1,
        float* __restrict__ hout, uint16_t* __restrict__ hjb) {
    int wid = (blockIdx.x * blockDim.x + threadIdx.x) >> 6;
    if (wid >= N_NODES) return;
    int i = wid;
    int lane = threadIdx.x & 63;
    int g = lane >> 3, h = lane & 7;
    const float4* rowi = (const float4*)(xw + (long)i * 64 + h * 8);
    float4 xi0 = rowi[0], xi1 = rowi[1];
    f32x2 xip[4] = {{xi0.x, xi0.y}, {xi0.z, xi0.w}, {xi1.x, xi1.y}, {xi1.z, xi1.w}};
    const float4* alp4 = (const float4*)(att_l + h * 8);
    float4 t0 = alp4[0], t1 = alp4[1];
    f32x2 atlp[4] = {{t0.x, t0.y}, {t0.z, t0.w}, {t1.x, t1.y}, {t1.z, t1.w}};
    const float4* arp4 = (const float4*)(att_r + h * 8);
    float4 u0 = arp4[0], u1 = arp4[1];
    f32x2 atrp[4] = {{u0.x, u0.y}, {u0.z, u0.w}, {u1.x, u1.y}, {u1.z, u1.w}};
    f32x2 prp = xip[0] * atrp[0];
    prp += xip[1] * atrp[1];
    prp += xip[2] * atrp[2];
    prp += xip[3] * atrp[3];
    float pr = prp.x + prp.y;
    f32x2 accp[4] = {{0.f,0.f},{0.f,0.f},{0.f,0.f},{0.f,0.f}};
    float den = 0.f;

#define C1_EDGE(XJP) do { \
    f32x2 qdp = xip[0] * (XJP)[0]; \
    qdp += xip[1] * (XJP)[1]; \
    qdp += xip[2] * (XJP)[2]; \
    qdp += xip[3] * (XJP)[3]; \
    f32x2 qlp = (XJP)[0] * atlp[0]; \
    qlp += (XJP)[1] * atlp[1]; \
    qlp += (XJP)[2] * atlp[2]; \
    qlp += (XJP)[3] * atlp[3]; \
    float qd = qdp.x + qdp.y, ql = qlp.x + qlp.y; \
    float a = (ql + pr) * fast_rcp(1.0f + __expf(-qd)); \
    a = fmaxf(a, 0.2f * a); \
    float e = __expf(a); \
    den += e; \
    f32x2 ev = {e, e}; \
    accp[0] += ev * (XJP)[0]; \
    accp[1] += ev * (XJP)[1]; \
    accp[2] += ev * (XJP)[2]; \
    accp[3] += ev * (XJP)[3]; \
} while (0)

    if (g == 0) C1_EDGE(xip);   // self loop
    int off = offs[i], dg = deg[i];
    int k = g;
    for (; k + 8 < dg; k += 16) {
        int j0 = csr8[off + k], j1 = csr8[off + k + 8];
        uint4 q0 = *(const uint4*)(xwb + (long)j0 * 8 + h * 8);
        uint4 q1 = *(const uint4*)(xwb + (long)j1 * 8 + h * 8);
        f32x2 ap[4] = {{blo(q0.x), bhi(q0.x)}, {blo(q0.y), bhi(q0.y)},
                       {blo(q0.z), bhi(q0.z)}, {blo(q0.w), bhi(q0.w)}};
        f32x2 bp[4] = {{blo(q1.x), bhi(q1.x)}, {blo(q1.y), bhi(q1.y)},
                       {blo(q1.z), bhi(q1.z)}, {blo(q1.w), bhi(q1.w)}};
        C1_EDGE(ap);
        C1_EDGE(bp);
    }
    if (k < dg) {
        int j0 = csr8[off + k];
        uint4 q0 = *(const uint4*)(xwb + (long)j0 * 8 + h * 8);
        f32x2 ap[4] = {{blo(q0.x), bhi(q0.x)}, {blo(q0.y), bhi(q0.y)},
                       {blo(q0.z), bhi(q0.z)}, {blo(q0.w), bhi(q0.w)}};
        C1_EDGE(ap);
    }
#undef C1_EDGE

    float acc[8] = {accp[0].x, accp[0].y, accp[1].x, accp[1].y,
                    accp[2].x, accp[2].y, accp[3].x, accp[3].y};
    #pragma unroll
    for (int o = 8; o <= 32; o <<= 1) {
        #pragma unroll
        for (int t = 0; t < 8; ++t) acc[t] += __shfl_xor(acc[t], o);
        den += __shfl_xor(den, o);
    }
    if (g == 0) {
        float inv = fast_rcp(den + 1e-16f);
        const float4* bp4 = (const float4*)(b1 + h * 8);
        float4 c0 = bp4[0], c1 = bp4[1];
        float4 o0, o1;
        float v;
        v = acc[0]*inv + c0.x; o0.x = v > 0.f ? v : __expf(v) - 1.0f;
        v = acc[1]*inv + c0.y; o0.y = v > 0.f ? v : __expf(v) - 1.0f;
        v = acc[2]*inv + c0.z; o0.z = v > 0.f ? v : __expf(v) - 1.0f;
        v = acc[3]*inv + c0.w; o0.w = v > 0.f ? v : __expf(v) - 1.0f;
        v = acc[4]*inv + c1.x; o1.x = v > 0.f ? v : __expf(v) - 1.0f;
        v = acc[5]*inv + c1.y; o1.y = v > 0.f ? v : __expf(v) - 1.0f;
        v = acc[6]*inv + c1.z; o1.z = v > 0.f ? v : __expf(v) - 1.0f;
        v = acc[7]*inv + c1.w; o1.w = v > 0.f ? v : __expf(v) - 1.0f;
        float4* po = (float4*)(hout + (long)i * 64 + h * 8);
        po[0] = o0; po[1] = o1;
        uint32_t d0 = f2bf(o0.x) | ((uint32_t)f2bf(o0.y) << 16);
        uint32_t d1 = f2bf(o0.z) | ((uint32_t)f2bf(o0.w) << 16);
        uint32_t d2 = f2bf(o1.x) | ((uint32_t)f2bf(o1.y) << 16);
        uint32_t d3 = f2bf(o1.z) | ((uint32_t)f2bf(o1.w) << 16);
        *(uint4*)(hjb + (long)i * 64 + h * 8) = make_uint4(d0, d1, d2, d3);
    }
}

// ---------- al/ar from hbuf via precomputed wl2/wr2 (f32, accurate) ----------
__global__ __launch_bounds__(256) void node_att2h(const float* __restrict__ hbuf,
        const float* __restrict__ wl2, const float* __restrict__ wr2,
        float* __restrict__ al, float* __restrict__ ar) {
    __shared__ float lw[512], lr[512];
    int tid = threadIdx.x;
    for (int t = tid; t < 512; t += 256) { lw[t] = wl2[t]; lr[t] = wr2[t]; }
    __syncthreads();
    int i = blockIdx.x * 256 + tid;
    if (i >= N_NODES) return;
    const float4* row = (const float4*)(hbuf + (long)i * 64);
    float sl[8] = {0,0,0,0,0,0,0,0}, sr[8] = {0,0,0,0,0,0,0,0};
    #pragma unroll
    for (int d4 = 0; d4 < 16; ++d4) {
        float4 v = row[d4];
        #pragma unroll
        for (int hh = 0; hh < 8; ++hh) {
            const float4 wv = *(const float4*)(lw + hh * 64 + d4 * 4);
            const float4 rv = *(const float4*)(lr + hh * 64 + d4 * 4);
            sl[hh] += v.x*wv.x + v.y*wv.y + v.z*wv.z + v.w*wv.w;
            sr[hh] += v.x*rv.x + v.y*rv.y + v.z*rv.z + v.w*rv.w;
        }
    }
    #pragma unroll
    for (int hh = 0; hh < 8; ++hh) {
        al[i * 8 + hh] = sl[hh];
        ar[i * 8 + hh] = sr[hh];
    }
}

// ---------- conv2 (h-space): wave-per-node; lane=(half, head lam, 16-dim slice r2);
//            logit = y_i.h_j (2 shuffles); agg in-lane; z = agg/(8*den) bf16,
//            written IN PLACE over Y row i. No LDS, no epilogue matmul here. ----------
__global__ __launch_bounds__(256) void conv2_node(const uint16_t* __restrict__ hjb16,
        const int* __restrict__ offs, const int* __restrict__ deg,
        const int* __restrict__ csr8, const float* __restrict__ al,
        const float* __restrict__ ar, uint32_t* __restrict__ Yd) {
    int wid = (blockIdx.x * 256 + threadIdx.x) >> 6;
    if (wid >= N_NODES) return;
    int i = wid;
    int lane = threadIdx.x & 63;
    int half = lane >> 5;
    int lam = lane & 7, r2 = (lane >> 3) & 3;
    const uint32_t* hjd = (const uint32_t*)hjb16;   // [N][32] dwords
    unsigned ydw = (unsigned)i * 256u + (unsigned)lam * 32u + (unsigned)r2 * 8u;

    // y_i slice: head lam, dims 16*r2..16*r2+15 (8 dwords bf16 -> 8 f32x2)
    f32x2 y[8];
    {
        uint4 a = *(const uint4*)(Yd + ydw);
        uint4 b = *(const uint4*)(Yd + ydw + 4);
        uint32_t d[8] = {a.x, a.y, a.z, a.w, b.x, b.y, b.z, b.w};
        #pragma unroll
        for (int t = 0; t < 8; ++t) y[t] = (f32x2){blo(d[t]), bhi(d[t])};
    }
    float ari = ar[i * 8 + lam];
    f32x2 agg[8];
    #pragma unroll
    for (int t = 0; t < 8; ++t) agg[t] = (f32x2){0.f, 0.f};
    float den = 0.f;
    int off = offs[i], dg = deg[i];

    auto CORE = [&](const uint32_t* D, float alv, bool valid) {
        f32x2 h[8];
        #pragma unroll
        for (int t = 0; t < 8; ++t) h[t] = (f32x2){blo(D[t]), bhi(D[t])};
        f32x2 pp = y[0] * h[0];
        #pragma unroll
        for (int t = 1; t < 8; ++t) pp += y[t] * h[t];
        float pd = pp.x + pp.y;
        pd += __shfl_xor(pd, 8);    // reduce over r2 (stays in half, lam fixed)
        pd += __shfl_xor(pd, 16);
        float a = (alv + ari) * fast_rcp(1.0f + __expf(-pd));
        a = fmaxf(a, 0.2f * a);
        float e = __expf(a);
        e = valid ? e : 0.f;
        den += e;
        f32x2 ev = {e, e};
        #pragma unroll
        for (int t = 0; t < 8; ++t) agg[t] += ev * h[t];
    };
    auto IDX = [&](int S) -> int {
        int e = half + 2 * S;
        int p = off + e;
        p = p < N_EDGES ? p : 0;
        int j = csr8[p];            // src*8
        return e < dg ? j : 0;
    };
    auto FETCH = [&](int j, uint32_t* D, float& A) {
        const uint32_t* r = hjd + (unsigned)j * 4u + (unsigned)r2 * 8u;
        uint4 a = *(const uint4*)(r);
        uint4 b = *(const uint4*)(r + 4);
        D[0] = a.x; D[1] = a.y; D[2] = a.z; D[3] = a.w;
        D[4] = b.x; D[5] = b.y; D[6] = b.z; D[7] = b.w;
        A = al[j + lam];
    };

    // self loop (half 0 only contributes)
    {
        uint32_t DS[8]; float AS;
        FETCH(i * 8, DS, AS);
        CORE(DS, AS, half == 0);
    }

    int nT = (dg + 1) >> 1;
    uint32_t D0[8], D1[8]; float A0, A1;
    { int j = IDX(0); FETCH(j, D0, A0); }
    { int j = IDX(1); FETCH(j, D1, A1); }
    int s = 0;
    while (s + 2 <= nT) {
        int j2 = IDX(s + 2);
        CORE(D0, A0, half + 2 * s < dg);
        FETCH(j2, D0, A0);
        int j3 = IDX(s + 3);
        CORE(D1, A1, half + 2 * (s + 1) < dg);
        FETCH(j3, D1, A1);
        s += 2;
    }
    if (s < nT)     CORE(D0, A0, half + 2 * s < dg);
    if (s + 1 < nT) CORE(D1, A1, half + 2 * (s + 1) < dg);

    // merge halves
    den += __shfl_xor(den, 32);
    #pragma unroll
    for (int t = 0; t < 8; ++t) {
        agg[t].x += __shfl_xor(agg[t].x, 32);
        agg[t].y += __shfl_xor(agg[t].y, 32);
    }
    float inv = 0.125f * fast_rcp(den + 1e-16f);
    if (half == 0) {
        uint32_t zd[8];
        #pragma unroll
        for (int t = 0; t < 8; ++t) {
            float zx = agg[t].x * inv, zy = agg[t].y * inv;
            zd[t] = f2bf(zx) | ((uint32_t)f2bf(zy) << 16);
        }
        *(uint4*)(Yd + ydw)     = make_uint4(zd[0], zd[1], zd[2], zd[3]);
        *(uint4*)(Yd + ydw + 4) = make_uint4(zd[4], zd[5], zd[6], zd[7]);
    }
}

// ---------- ZGEMM: out = Z @ B + b2, fused row log_softmax ----------
__global__ __launch_bounds__(512) void zgemm_mfma(const uint32_t* __restrict__ Zd,
        const uint16_t* __restrict__ w2z, const float* __restrict__ b2,
        float* __restrict__ out) {
    __shared__ __align__(16) uint16_t Bsm[48 * 520];
    int tid = threadIdx.x;
    int l = tid & 63, w = tid >> 6;
    long base = (long)blockIdx.x * 128;
    for (int q = tid; q < 3072; q += 512) {
        int c = q >> 6, k8 = (q & 63) * 8;
        *(uint4*)(Bsm + c * 520 + k8) = *(const uint4*)(w2z + c * 512 + k8);
    }
    if (blockIdx.x == 0 && tid == 0) out[(long)N_NODES * 40] = 0.0f;  // att_loss
    __syncthreads();
    long n0 = base + w * 16 + (l & 15);
    long nld = n0 < N_NODES ? n0 : N_NODES - 1;
    f32x4 acc[3];
    #pragma unroll
    for (int ct = 0; ct < 3; ++ct)
        #pragma unroll
        for (int j = 0; j < 4; ++j) acc[ct][j] = 0.f;
    #pragma unroll
    for (int kb = 0; kb < 16; ++kb) {
        bf16x8 a = *(const bf16x8*)(Zd + nld * 256 + kb * 16 + (l >> 4) * 4);
        #pragma unroll
        for (int ct = 0; ct < 3; ++ct) {
            bf16x8 b = *(const bf16x8*)(Bsm + (ct * 16 + (l & 15)) * 520 + kb * 32 + (l >> 4) * 8);
            acc[ct] = __builtin_amdgcn_mfma_f32_16x16x32_bf16(b, a, acc[ct], 0, 0, 0);
        }
    }
    // lane holds cols cb = ct*16 + (l>>4)*4 + j for node n0; valid iff cb < 40
    float v[12];
    int cb0 = (l >> 4) * 4;
    #pragma unroll
    for (int ct = 0; ct < 3; ++ct)
        #pragma unroll
        for (int j = 0; j < 4; ++j) {
            int cb = ct * 16 + cb0 + j;
            v[ct * 4 + j] = (cb < 40) ? acc[ct][j] + b2[cb] : -1e30f;
        }
    float mx = v[0];
    #pragma unroll
    for (int t = 1; t < 12; ++t) mx = fmaxf(mx, v[t]);
    mx = fmaxf(mx, __shfl_xor(mx, 16));
    mx = fmaxf(mx, __shfl_xor(mx, 32));
    float sm = 0.f;
    #pragma unroll
    for (int t = 0; t < 12; ++t) sm += (v[t] > -1e29f) ? __expf(v[t] - mx) : 0.f;
    sm += __shfl_xor(sm, 16);
    sm += __shfl_xor(sm, 32);
    float lse = mx + __logf(sm);
    if (n0 < N_NODES) {
        #pragma unroll
        for (int ct = 0; ct < 3; ++ct)
            #pragma unroll
            for (int j = 0; j < 4; ++j) {
                int cb = ct * 16 + cb0 + j;
                if (cb < 40) out[n0 * 40 + cb] = v[ct * 4 + j] - lse;
            }
    }
}

extern "C" void kernel_launch(void* const* d_in, const int* in_sizes, int n_in,
                              void* d_out, int out_size, void* d_ws, size_t ws_size,
                              hipStream_t stream) {
    const float* x      = (const float*)d_in[0];
    const int*   ei     = (const int*)d_in[1];
    const float* W1     = (const float*)d_in[2];
    const float* att_l1 = (const float*)d_in[3];
    const float* att_r1 = (const float*)d_in[4];
    const float* b1     = (const float*)d_in[5];
    const float* W2     = (const float*)d_in[6];
    const float* att_l2 = (const float*)d_in[7];
    const float* att_r2 = (const float*)d_in[8];
    const float* b2     = (const float*)d_in[9];
    const int* src = ei;
    const int* dst = ei + N_EDGES;
    float* out = (float*)d_out;

    char* ws = (char*)d_ws;
    // Y (102.4 MB) aliases xw1 (25.6) + hbuf (25.6) + xw1b (12.8): all dead
    // before ygemm writes Y. conv2 overwrites Y rows in place with Z.
    uint16_t* Y      = (uint16_t*)(ws + 0);          // 102.4 MB (later: Z)
    float*    xw1    = (float*)(ws + 0);             // 25.6 MB (dead after conv1)
    float*    hbuf   = (float*)(ws + 25600000);      // 25.6 MB (dead after node_att2h)
    uint16_t* xw1b   = (uint16_t*)(ws + 51200000);   // 12.8 MB (dead after conv1)
    uint16_t* hjb    = (uint16_t*)(ws + 102400000);  // 12.8 MB (bf16 h rows)
    float*    al     = (float*)(ws + 115200000);     // 3.2 MB
    float*    ar     = (float*)(ws + 118400000);     // 3.2 MB
    int*      deg    = (int*)(ws + 121600000);       // 400 KB
    int*      offs   = (int*)(ws + 122000000);       // 400 KB
    int*      cursor = (int*)(ws + 122400000);       // 400 KB
    int*      btot   = (int*)(ws + 122800000);       // 1 KB
    int*      csr8   = (int*)(ws + 122801024);       // 6.4 MB
    uint16_t* w1hi   = (uint16_t*)(ws + 129201024);  // 64 KB
    uint16_t* w1lo   = (uint16_t*)(ws + 129266560);  // 64 KB
    uint16_t* mhi    = (uint16_t*)(ws + 129332096);  // 64 KB
    uint16_t* mlo    = (uint16_t*)(ws + 129397632);  // 64 KB
    uint16_t* w2z    = (uint16_t*)(ws + 129463168);  // 48 KB
    float*    wl2    = (float*)(ws + 129512320);     // 2 KB
    float*    wr2    = (float*)(ws + 129514368);     // 2 KB -> ~129.5 MB total

    hipMemsetAsync(deg, 0, (size_t)N_NODES * 4, stream);

    // weight prep (independent of CSR)
    cvt_w1<<<16, 256, 0, stream>>>(W1, w1hi, w1lo);
    wvec_k<<<2, 256, 0, stream>>>(W2, att_l2, att_r2, wl2, wr2);
    mcat_k<<<8, 512, 0, stream>>>(W2, mhi, mlo);
    w2z_k<<<96, 256, 0, stream>>>(W2, w2z);

    // CSR build (dst-sorted adjacency; csr stores src*8)
    hist_k<<<6250, 256, 0, stream>>>(dst, deg);
    scan_a<<<SCAN_NB, 512, 0, stream>>>(deg, offs, btot);
    scan_b<<<1, 256, 0, stream>>>(btot);
    scan_c<<<SCAN_NB, 512, 0, stream>>>(offs, btot, cursor);
    scatter_k<<<6250, 256, 0, stream>>>(src, dst, cursor, csr8);

    // conv1
    gemm1_mfma<<<782, 512, 0, stream>>>(x, w1hi, w1lo, xw1, xw1b);
    conv1_node<<<25000, 256, 0, stream>>>(xw1, xw1b, offs, deg, csr8,
                                          att_l1, att_r1, b1, hbuf, hjb);
    node_att2h<<<391, 256, 0, stream>>>(hbuf, wl2, wr2, al, ar);

    // Y = h @ Mcat (after node_att2h: Y aliases xw1/hbuf/xw1b)
    ygemm_mfma<<<1564, 512, 0, stream>>>(hjb, mhi, mlo, Y);

    // conv2: h-space attention; writes Z in place over Y
    conv2_node<<<25000, 256, 0, stream>>>(hjb, offs, deg, csr8, al, ar, (uint32_t*)Y);

    // out = Z @ B + b2, fused log_softmax
    zgemm_mfma<<<782, 512, 0, stream>>>((const uint32_t*)Y, w2z, b2, out);
}

// Round 6
// 561.582 us; speedup vs baseline: 1.4761x; 1.0065x over previous
//
#include <hip/hip_runtime.h>
#include <cstdint>

#define N_NODES 100000
#define N_EDGES 1600000
#define SCAN_NB 196   // ceil(100000/512)

typedef short bf16x8 __attribute__((ext_vector_type(8)));
typedef float f32x4 __attribute__((ext_vector_type(4)));
typedef float f32x2 __attribute__((ext_vector_type(2)));   // -> v_pk_fma_f32

// ---------- bf16 helpers ----------
__device__ __forceinline__ uint16_t f2bf(float f) {
    uint32_t b = __float_as_uint(f);
    return (uint16_t)((b + 0x7fffu + ((b >> 16) & 1u)) >> 16);  // RNE
}
__device__ __forceinline__ float bfval(uint16_t u) {
    return __uint_as_float(((uint32_t)u) << 16);
}
__device__ __forceinline__ float blo(uint32_t u) { return __uint_as_float(u << 16); }
__device__ __forceinline__ float bhi(uint32_t u) { return __uint_as_float(u & 0xffff0000u); }

__device__ __forceinline__ float fast_rcp(float x) { return __builtin_amdgcn_rcpf(x); }
// butterfly adds via ds_swizzle with literal patterns (no VALU addr setup)
__device__ __forceinline__ float swz_xadd8(float x) {
    int s = __builtin_amdgcn_ds_swizzle(__float_as_int(x), 0x201F);  // lane^8
    return x + __int_as_float(s);
}
__device__ __forceinline__ float swz_xadd16(float x) {
    int s = __builtin_amdgcn_ds_swizzle(__float_as_int(x), 0x401F);  // lane^16
    return x + __int_as_float(s);
}

// ---------- fused weight prep: cvt_w1 | wvec | w2z | mcat ----------
__global__ __launch_bounds__(512) void prep_k(const float* __restrict__ W1,
        const float* __restrict__ W2, const float* __restrict__ attl,
        const float* __restrict__ attr,
        uint16_t* __restrict__ w1hi, uint16_t* __restrict__ w1lo,
        float* __restrict__ wl2, float* __restrict__ wr2,
        uint16_t* __restrict__ w2z, uint16_t* __restrict__ mhi,
        uint16_t* __restrict__ mlo) {
    __shared__ float Wh[64 * 40];
    int b = blockIdx.x, tid = threadIdx.x;
    if (b < 8) {                       // cvt_w1: 4096 work-items
        int gid = b * 512 + tid;
        int c = gid & 63, kg = gid >> 6;
        uint32_t dh[4], dl[4];
        #pragma unroll
        for (int t = 0; t < 4; ++t) {
            float v0 = W1[(kg * 8 + 2 * t) * 64 + c];
            float v1 = W1[(kg * 8 + 2 * t + 1) * 64 + c];
            uint16_t h0 = f2bf(v0), h1 = f2bf(v1);
            uint16_t l0 = f2bf(v0 - bfval(h0)), l1 = f2bf(v1 - bfval(h1));
            dh[t] = h0 | ((uint32_t)h1 << 16);
            dl[t] = l0 | ((uint32_t)l1 << 16);
        }
        *(uint4*)(w1hi + (long)c * 512 + kg * 8) = make_uint4(dh[0], dh[1], dh[2], dh[3]);
        *(uint4*)(w1lo + (long)c * 512 + kg * 8) = make_uint4(dl[0], dl[1], dl[2], dl[3]);
    } else if (b == 8) {               // wvec: 512 items
        int h = tid >> 6, k = tid & 63;
        float sl = 0.f, sr = 0.f;
        #pragma unroll 8
        for (int c = 0; c < 40; ++c) {
            float w = W2[k * 320 + h * 40 + c];
            sl += w * attl[h * 40 + c];
            sr += w * attr[h * 40 + c];
        }
        wl2[tid] = sl; wr2[tid] = sr;
    } else if (b < 57) {               // w2z: 24576 items
        int t = (b - 9) * 512 + tid;
        int c = t >> 9, kap = t & 511;
        int h = kap >> 6, k = kap & 63;
        float v = (c < 40) ? W2[k * 320 + h * 40 + c] : 0.f;
        w2z[c * 512 + kap] = f2bf(v);
    } else {                           // mcat: blocks 57..64, one head each
        int h = b - 57;
        for (int t = tid; t < 2560; t += 512) {
            int k = t / 40, c = t % 40;
            Wh[k * 40 + c] = W2[k * 320 + h * 40 + c];
        }
        __syncthreads();
        #pragma unroll
        for (int r = 0; r < 8; ++r) {
            int o = r * 512 + tid;
            int kp = o >> 6, k = o & 63;
            float s = 0.f;
            #pragma unroll 8
            for (int c = 0; c < 40; ++c) s += Wh[k * 40 + c] * Wh[kp * 40 + c];
            uint16_t hi = f2bf(s);
            uint16_t lo = f2bf(s - bfval(hi));
            mhi[(h * 64 + kp) * 64 + k] = hi;
            mlo[(h * 64 + kp) * 64 + k] = lo;
        }
    }
}

// ---------- GEMM1 (split-bf16 MFMA): xw1 f32 + xw1b bf16 mirror ----------
__global__ __launch_bounds__(512) void gemm1_mfma(const float* __restrict__ x,
        const uint16_t* __restrict__ w1hi, const uint16_t* __restrict__ w1lo,
        float* __restrict__ xw1, uint16_t* __restrict__ xw1b) {
    __shared__ __align__(16) char Ah[128 * 144];
    __shared__ __align__(16) char Al[128 * 144];
    __shared__ __align__(16) char Bh[64 * 144];
    __shared__ __align__(16) char Bl[64 * 144];
    int tid = threadIdx.x;
    int l = tid & 63, w = tid >> 6;
    long base = (long)blockIdx.x * 128;
    f32x4 acc[4];
    #pragma unroll
    for (int ct = 0; ct < 4; ++ct)
        #pragma unroll
        for (int j = 0; j < 4; ++j) acc[ct][j] = 0.f;

    for (int kb = 0; kb < 512; kb += 64) {
        __syncthreads();
        #pragma unroll
        for (int it = 0; it < 2; ++it) {
            int idx = tid + it * 512;
            int row = idx >> 3, kc = idx & 7;
            long r = base + row; if (r >= N_NODES) r = N_NODES - 1;
            const float4* p = (const float4*)(x + r * 512 + kb + kc * 8);
            float4 f0 = p[0], f1 = p[1];
            float v[8] = {f0.x, f0.y, f0.z, f0.w, f1.x, f1.y, f1.z, f1.w};
            uint32_t dh[4], dl[4];
            #pragma unroll
            for (int t = 0; t < 4; ++t) {
                uint16_t h0 = f2bf(v[2 * t]),     h1 = f2bf(v[2 * t + 1]);
                uint16_t l0 = f2bf(v[2 * t] - bfval(h0));
                uint16_t l1 = f2bf(v[2 * t + 1] - bfval(h1));
                dh[t] = h0 | ((uint32_t)h1 << 16);
                dl[t] = l0 | ((uint32_t)l1 << 16);
            }
            *(uint4*)(Ah + row * 144 + kc * 16) = make_uint4(dh[0], dh[1], dh[2], dh[3]);
            *(uint4*)(Al + row * 144 + kc * 16) = make_uint4(dl[0], dl[1], dl[2], dl[3]);
        }
        {
            int c = tid >> 3, kc = tid & 7;
            *(uint4*)(Bh + c * 144 + kc * 16) =
                *(const uint4*)(w1hi + (long)c * 512 + kb + kc * 8);
            *(uint4*)(Bl + c * 144 + kc * 16) =
                *(const uint4*)(w1lo + (long)c * 512 + kb + kc * 8);
        }
        __syncthreads();
        #pragma unroll
        for (int kk = 0; kk < 2; ++kk) {
            int aoff = (w * 16 + (l & 15)) * 144 + kk * 64 + (l >> 4) * 16;
            bf16x8 ah = *(const bf16x8*)(Ah + aoff);
            bf16x8 alo = *(const bf16x8*)(Al + aoff);
            #pragma unroll
            for (int ct = 0; ct < 4; ++ct) {
                int boff = (ct * 16 + (l & 15)) * 144 + kk * 64 + (l >> 4) * 16;
                bf16x8 bh = *(const bf16x8*)(Bh + boff);
                bf16x8 bl = *(const bf16x8*)(Bl + boff);
                acc[ct] = __builtin_amdgcn_mfma_f32_16x16x32_bf16(ah, bh, acc[ct], 0, 0, 0);
                acc[ct] = __builtin_amdgcn_mfma_f32_16x16x32_bf16(alo, bh, acc[ct], 0, 0, 0);
                acc[ct] = __builtin_amdgcn_mfma_f32_16x16x32_bf16(ah, bl, acc[ct], 0, 0, 0);
            }
        }
    }
    int nrow = w * 16 + (l >> 4) * 4;
    #pragma unroll
    for (int ct = 0; ct < 4; ++ct)
        #pragma unroll
        for (int j = 0; j < 4; ++j) {
            long node = base + nrow + j;
            if (node < N_NODES) {
                int col = ct * 16 + (l & 15);
                xw1[node * 64 + col] = acc[ct][j];
                xw1b[node * 64 + col] = f2bf(acc[ct][j]);
            }
        }
}

// ---------- YGEMM: Y[i][kappa'] = h_bf16 @ Mcat(split), plain [i][kappa] bf16 ----------
__global__ __launch_bounds__(512) void ygemm_mfma(const uint16_t* __restrict__ hjb,
        const uint16_t* __restrict__ mhi, const uint16_t* __restrict__ mlo,
        uint16_t* __restrict__ Y16) {
    __shared__ __align__(16) char Bh[256 * 144];
    __shared__ __align__(16) char Bl[256 * 144];
    int tid = threadIdx.x;
    int l = tid & 63, w = tid >> 6;
    int half = blockIdx.x & 1;
    long base = (long)(blockIdx.x >> 1) * 128;
    #pragma unroll
    for (int it = 0; it < 4; ++it) {
        int idx = tid + it * 512;
        int c = idx >> 3, kc = idx & 7;
        *(uint4*)(Bh + c * 144 + kc * 16) =
            *(const uint4*)(mhi + (long)(half * 256 + c) * 64 + kc * 8);
        *(uint4*)(Bl + c * 144 + kc * 16) =
            *(const uint4*)(mlo + (long)(half * 256 + c) * 64 + kc * 8);
    }
    long n0 = base + w * 16 + (l & 15);
    long nld = n0 < N_NODES ? n0 : N_NODES - 1;
    bf16x8 a[2];
    #pragma unroll
    for (int kk = 0; kk < 2; ++kk)
        a[kk] = *(const bf16x8*)(hjb + nld * 64 + kk * 32 + (l >> 4) * 8);
    __syncthreads();
    f32x4 acc[16];
    #pragma unroll
    for (int ct = 0; ct < 16; ++ct)
        #pragma unroll
        for (int j = 0; j < 4; ++j) acc[ct][j] = 0.f;
    #pragma unroll
    for (int ct = 0; ct < 16; ++ct) {
        #pragma unroll
        for (int kk = 0; kk < 2; ++kk) {
            bf16x8 bh = *(const bf16x8*)(Bh + (ct * 16 + (l & 15)) * 144 + kk * 64 + (l >> 4) * 16);
            bf16x8 bl = *(const bf16x8*)(Bl + (ct * 16 + (l & 15)) * 144 + kk * 64 + (l >> 4) * 16);
            acc[ct] = __builtin_amdgcn_mfma_f32_16x16x32_bf16(bh, a[kk], acc[ct], 0, 0, 0);
            acc[ct] = __builtin_amdgcn_mfma_f32_16x16x32_bf16(bl, a[kk], acc[ct], 0, 0, 0);
        }
    }
    if (n0 < N_NODES) {
        uint32_t* Yd = (uint32_t*)Y16;
        #pragma unroll
        for (int ct = 0; ct < 16; ++ct) {
            int kp = half * 256 + ct * 16 + (l >> 4) * 4;   // kappa' of acc[ct][0]
            uint32_t d0 = f2bf(acc[ct][0]) | ((uint32_t)f2bf(acc[ct][1]) << 16);
            uint32_t d1 = f2bf(acc[ct][2]) | ((uint32_t)f2bf(acc[ct][3]) << 16);
            Yd[n0 * 256 + (kp >> 1)]     = d0;
            Yd[n0 * 256 + (kp >> 1) + 1] = d1;
        }
    }
}

// ---------- CSR build (csr stores src*8) ----------
__global__ void hist_k(const int* __restrict__ dst, int* __restrict__ deg) {
    int e = blockIdx.x * blockDim.x + threadIdx.x;
    if (e < N_EDGES) atomicAdd(&deg[dst[e]], 1);
}

__global__ __launch_bounds__(512) void scan_a(const int* __restrict__ deg,
        int* __restrict__ offs, int* __restrict__ btot) {
    __shared__ int sh[512];
    int t = threadIdx.x;
    int g = blockIdx.x * 512 + t;
    int v = (g < N_NODES) ? deg[g] : 0;
    sh[t] = v;
    __syncthreads();
    #pragma unroll
    for (int o = 1; o < 512; o <<= 1) {
        int add = (t >= o) ? sh[t - o] : 0;
        __syncthreads();
        sh[t] += add;
        __syncthreads();
    }
    if (g < N_NODES) offs[g] = sh[t] - v;
    if (t == 511) btot[blockIdx.x] = sh[511];
}

__global__ __launch_bounds__(256) void scan_b(int* __restrict__ btot) {
    __shared__ int sh[256];
    int t = threadIdx.x;
    int v = (t < SCAN_NB) ? btot[t] : 0;
    sh[t] = v;
    __syncthreads();
    #pragma unroll
    for (int o = 1; o < 256; o <<= 1) {
        int add = (t >= o) ? sh[t - o] : 0;
        __syncthreads();
        sh[t] += add;
        __syncthreads();
    }
    if (t < SCAN_NB) btot[t] = sh[t] - v;
}

__global__ __launch_bounds__(512) void scan_c(int* __restrict__ offs,
        const int* __restrict__ btot, int* __restrict__ cursor) {
    int g = blockIdx.x * 512 + threadIdx.x;
    if (g < N_NODES) {
        int o = offs[g] + btot[blockIdx.x];
        offs[g] = o;
        cursor[g] = o;
    }
}

__global__ void scatter_k(const int* __restrict__ src, const int* __restrict__ dst,
        int* __restrict__ cursor, int* __restrict__ csr8) {
    int e = blockIdx.x * blockDim.x + threadIdx.x;
    if (e < N_EDGES) {
        int pos = atomicAdd(&cursor[dst[e]], 1);
        csr8[pos] = src[e] << 3;
    }
}

// ---------- conv1: head-per-lane; bf16 gathers; fused al/ar epilogue ----------
__global__ __launch_bounds__(256) void conv1_node(const float* __restrict__ xw,
        const uint16_t* __restrict__ xwb,
        const int* __restrict__ offs, const int* __restrict__ deg,
        const int* __restrict__ csr8, const float* __restrict__ att_l,
        const float* __restrict__ att_r, const float* __restrict__ b1,
        const float* __restrict__ wl2, const float* __restrict__ wr2,
        uint16_t* __restrict__ hjb, float* __restrict__ al, float* __restrict__ ar) {
    int wid = (blockIdx.x * blockDim.x + threadIdx.x) >> 6;
    if (wid >= N_NODES) return;
    int i = wid;
    int lane = threadIdx.x & 63;
    int g = lane >> 3, h = lane & 7;
    const float4* rowi = (const float4*)(xw + (long)i * 64 + h * 8);
    float4 xi0 = rowi[0], xi1 = rowi[1];
    f32x2 xip[4] = {{xi0.x, xi0.y}, {xi0.z, xi0.w}, {xi1.x, xi1.y}, {xi1.z, xi1.w}};
    const float4* alp4 = (const float4*)(att_l + h * 8);
    float4 t0 = alp4[0], t1 = alp4[1];
    f32x2 atlp[4] = {{t0.x, t0.y}, {t0.z, t0.w}, {t1.x, t1.y}, {t1.z, t1.w}};
    const float4* arp4 = (const float4*)(att_r + h * 8);
    float4 u0 = arp4[0], u1 = arp4[1];
    f32x2 atrp[4] = {{u0.x, u0.y}, {u0.z, u0.w}, {u1.x, u1.y}, {u1.z, u1.w}};
    f32x2 prp = xip[0] * atrp[0];
    prp += xip[1] * atrp[1];
    prp += xip[2] * atrp[2];
    prp += xip[3] * atrp[3];
    float pr = prp.x + prp.y;
    f32x2 accp[4] = {{0.f,0.f},{0.f,0.f},{0.f,0.f},{0.f,0.f}};
    float den = 0.f;

#define C1_EDGE(XJP) do { \
    f32x2 qdp = xip[0] * (XJP)[0]; \
    qdp += xip[1] * (XJP)[1]; \
    qdp += xip[2] * (XJP)[2]; \
    qdp += xip[3] * (XJP)[3]; \
    f32x2 qlp = (XJP)[0] * atlp[0]; \
    qlp += (XJP)[1] * atlp[1]; \
    qlp += (XJP)[2] * atlp[2]; \
    qlp += (XJP)[3] * atlp[3]; \
    float qd = qdp.x + qdp.y, ql = qlp.x + qlp.y; \
    float a = (ql + pr) * fast_rcp(1.0f + __expf(-qd)); \
    a = fmaxf(a, 0.2f * a); \
    float e = __expf(a); \
    den += e; \
    f32x2 ev = {e, e}; \
    accp[0] += ev * (XJP)[0]; \
    accp[1] += ev * (XJP)[1]; \
    accp[2] += ev * (XJP)[2]; \
    accp[3] += ev * (XJP)[3]; \
} while (0)

    if (g == 0) C1_EDGE(xip);   // self loop
    int off = offs[i], dg = deg[i];
    int k = g;
    for (; k + 8 < dg; k += 16) {
        int j0 = csr8[off + k], j1 = csr8[off + k + 8];
        uint4 q0 = *(const uint4*)(xwb + (long)j0 * 8 + h * 8);
        uint4 q1 = *(const uint4*)(xwb + (long)j1 * 8 + h * 8);
        f32x2 ap[4] = {{blo(q0.x), bhi(q0.x)}, {blo(q0.y), bhi(q0.y)},
                       {blo(q0.z), bhi(q0.z)}, {blo(q0.w), bhi(q0.w)}};
        f32x2 bp[4] = {{blo(q1.x), bhi(q1.x)}, {blo(q1.y), bhi(q1.y)},
                       {blo(q1.z), bhi(q1.z)}, {blo(q1.w), bhi(q1.w)}};
        C1_EDGE(ap);
        C1_EDGE(bp);
    }
    if (k < dg) {
        int j0 = csr8[off + k];
        uint4 q0 = *(const uint4*)(xwb + (long)j0 * 8 + h * 8);
        f32x2 ap[4] = {{blo(q0.x), bhi(q0.x)}, {blo(q0.y), bhi(q0.y)},
                       {blo(q0.z), bhi(q0.z)}, {blo(q0.w), bhi(q0.w)}};
        C1_EDGE(ap);
    }
#undef C1_EDGE

    float acc[8] = {accp[0].x, accp[0].y, accp[1].x, accp[1].y,
                    accp[2].x, accp[2].y, accp[3].x, accp[3].y};
    #pragma unroll
    for (int o = 8; o <= 32; o <<= 1) {
        #pragma unroll
        for (int t = 0; t < 8; ++t) acc[t] += __shfl_xor(acc[t], o);
        den += __shfl_xor(den, o);
    }
    // all lanes now hold the full sums for head h -> compute ELU'd h-row slice
    float inv = fast_rcp(den + 1e-16f);
    const float4* bp4 = (const float4*)(b1 + h * 8);
    float4 c0 = bp4[0], c1 = bp4[1];
    float bias[8] = {c0.x, c0.y, c0.z, c0.w, c1.x, c1.y, c1.z, c1.w};
    float ov[8];
    #pragma unroll
    for (int t = 0; t < 8; ++t) {
        float v = acc[t] * inv + bias[t];
        ov[t] = v > 0.f ? v : __expf(v) - 1.0f;
    }
    if (g == 0) {
        uint32_t d0 = f2bf(ov[0]) | ((uint32_t)f2bf(ov[1]) << 16);
        uint32_t d1 = f2bf(ov[2]) | ((uint32_t)f2bf(ov[3]) << 16);
        uint32_t d2 = f2bf(ov[4]) | ((uint32_t)f2bf(ov[5]) << 16);
        uint32_t d3 = f2bf(ov[6]) | ((uint32_t)f2bf(ov[7]) << 16);
        *(uint4*)(hjb + (long)i * 64 + h * 8) = make_uint4(d0, d1, d2, d3);
    }
    // fused al/ar: lane (g,h) dots its 8 h-vals with wl2[g][h*8..], reduce over h
    {
        const float4* wlp = (const float4*)(wl2 + g * 64 + h * 8);
        float4 w0 = wlp[0], w1 = wlp[1];
        const float4* wrp = (const float4*)(wr2 + g * 64 + h * 8);
        float4 r0 = wrp[0], r1 = wrp[1];
        float sl = ov[0]*w0.x + ov[1]*w0.y + ov[2]*w0.z + ov[3]*w0.w
                 + ov[4]*w1.x + ov[5]*w1.y + ov[6]*w1.z + ov[7]*w1.w;
        float sr = ov[0]*r0.x + ov[1]*r0.y + ov[2]*r0.z + ov[3]*r0.w
                 + ov[4]*r1.x + ov[5]*r1.y + ov[6]*r1.z + ov[7]*r1.w;
        #pragma unroll
        for (int o = 1; o <= 4; o <<= 1) {
            sl += __shfl_xor(sl, o);
            sr += __shfl_xor(sr, o);
        }
        if (h == 0) {
            al[i * 8 + g] = sl;
            ar[i * 8 + g] = sr;
        }
    }
}

// ---------- conv2 (h-space): wave-per-node; ungated pair loop; ds_swizzle reduce;
//            z = agg/(8*den) bf16 written in place over Y row i ----------
__global__ __launch_bounds__(256) void conv2_node(const uint16_t* __restrict__ hjb16,
        const int* __restrict__ offs, const int* __restrict__ deg,
        const int* __restrict__ csr8, const float* __restrict__ al,
        const float* __restrict__ ar, uint32_t* __restrict__ Yd) {
    int wid = (blockIdx.x * 256 + threadIdx.x) >> 6;
    if (wid >= N_NODES) return;
    int i = wid;
    int lane = threadIdx.x & 63;
    int half = lane >> 5;
    int lam = lane & 7, r2 = (lane >> 3) & 3;
    const uint4* hj4 = (const uint4*)hjb16;        // 8 uint4 per row
    int r22 = r2 * 2;
    unsigned ydw = (unsigned)i * 256u + (unsigned)lam * 32u + (unsigned)r2 * 8u;

    // y_i slice: head lam, dims 16*r2..16*r2+15
    f32x2 y[8];
    {
        uint4 a = *(const uint4*)(Yd + ydw);
        uint4 b = *(const uint4*)(Yd + ydw + 4);
        uint32_t d[8] = {a.x, a.y, a.z, a.w, b.x, b.y, b.z, b.w};
        #pragma unroll
        for (int t = 0; t < 8; ++t) y[t] = (f32x2){blo(d[t]), bhi(d[t])};
    }
    float ari = ar[i * 8 + lam];
    f32x2 agg[8];
    #pragma unroll
    for (int t = 0; t < 8; ++t) agg[t] = (f32x2){0.f, 0.f};
    float den = 0.f;
    int off = offs[i], dg = deg[i];

    auto CORE = [&](const uint32_t* D, float alv) {
        f32x2 h[8];
        #pragma unroll
        for (int t = 0; t < 8; ++t) h[t] = (f32x2){blo(D[t]), bhi(D[t])};
        f32x2 pp = y[0] * h[0];
        #pragma unroll
        for (int t = 1; t < 8; ++t) pp += y[t] * h[t];
        float pd = pp.x + pp.y;
        pd = swz_xadd8(pd);
        pd = swz_xadd16(pd);
        float a = (alv + ari) * fast_rcp(1.0f + __expf(-pd));
        a = fmaxf(a, 0.2f * a);
        float e = __expf(a);
        den += e;
        f32x2 ev = {e, e};
        #pragma unroll
        for (int t = 0; t < 8; ++t) agg[t] += ev * h[t];
    };
    auto COREG = [&](const uint32_t* D, float alv, bool valid) {
        f32x2 h[8];
        #pragma unroll
        for (int t = 0; t < 8; ++t) h[t] = (f32x2){blo(D[t]), bhi(D[t])};
        f32x2 pp = y[0] * h[0];
        #pragma unroll
        for (int t = 1; t < 8; ++t) pp += y[t] * h[t];
        float pd = pp.x + pp.y;
        pd = swz_xadd8(pd);
        pd = swz_xadd16(pd);
        float a = (alv + ari) * fast_rcp(1.0f + __expf(-pd));
        a = fmaxf(a, 0.2f * a);
        float e = __expf(a);
        e = valid ? e : 0.f;
        den += e;
        f32x2 ev = {e, e};
        #pragma unroll
        for (int t = 0; t < 8; ++t) agg[t] += ev * h[t];
    };
    auto PF = [&](int p, uint32_t* D, float& A) {
        p = p < N_EDGES ? p : N_EDGES - 1;         // abs-position clamp only
        int j = csr8[p];                           // src*8
        const uint4* r = hj4 + (unsigned)j + r22;
        uint4 a = r[0], b = r[1];
        D[0] = a.x; D[1] = a.y; D[2] = a.z; D[3] = a.w;
        D[4] = b.x; D[5] = b.y; D[6] = b.z; D[7] = b.w;
        A = al[j + lam];
    };

    // self loop (half 0 only contributes)
    {
        uint32_t DS[8]; float AS;
        const uint4* r = hj4 + (unsigned)i * 8u + r22;
        uint4 a = r[0], b = r[1];
        DS[0] = a.x; DS[1] = a.y; DS[2] = a.z; DS[3] = a.w;
        DS[4] = b.x; DS[5] = b.y; DS[6] = b.z; DS[7] = b.w;
        AS = al[i * 8 + lam];
        COREG(DS, AS, half == 0);
    }

    int nP = dg >> 1;                 // full pairs: positions 2s+half all valid
    int base = off + half;
    uint32_t R0[8], R1[8], T0[8], T1[8];
    float A0, A1, B0, B1;
    PF(base,     R0, A0);
    PF(base + 2, R1, A1);
    int s = 0;
    while (s + 4 <= nP) {             // ping-pong, no rotation copies
        PF(base + 2*s + 4,  T0, B0); CORE(R0, A0);
        PF(base + 2*s + 6,  T1, B1); CORE(R1, A1);
        PF(base + 2*s + 8,  R0, A0); CORE(T0, B0);
        PF(base + 2*s + 10, R1, A1); CORE(T1, B1);
        s += 4;
    }
    int rem = nP - s;                 // 0..3; R0=pair s, R1=pair s+1
    if (rem >= 2) {
        PF(base + 2*s + 4, T0, B0);
        CORE(R0, A0);
        CORE(R1, A1);
        if (rem == 3) CORE(T0, B0);
    } else if (rem == 1) {
        CORE(R0, A0);
    }
    if (dg & 1) {                     // odd tail: position dg-1, half 0 only
        uint32_t RT[8]; float AT;
        PF(off + dg - 1, RT, AT);
        COREG(RT, AT, half == 0);
    }

    // merge halves
    den += __shfl_xor(den, 32);
    #pragma unroll
    for (int t = 0; t < 8; ++t) {
        agg[t].x += __shfl_xor(agg[t].x, 32);
        agg[t].y += __shfl_xor(agg[t].y, 32);
    }
    float inv = 0.125f * fast_rcp(den + 1e-16f);
    if (half == 0) {
        uint32_t zd[8];
        #pragma unroll
        for (int t = 0; t < 8; ++t) {
            float zx = agg[t].x * inv, zy = agg[t].y * inv;
            zd[t] = f2bf(zx) | ((uint32_t)f2bf(zy) << 16);
        }
        *(uint4*)(Yd + ydw)     = make_uint4(zd[0], zd[1], zd[2], zd[3]);
        *(uint4*)(Yd + ydw + 4) = make_uint4(zd[4], zd[5], zd[6], zd[7]);
    }
}

// ---------- ZGEMM: out = Z @ B + b2, fused row log_softmax ----------
__global__ __launch_bounds__(512) void zgemm_mfma(const uint32_t* __restrict__ Zd,
        const uint16_t* __restrict__ w2z, const float* __restrict__ b2,
        float* __restrict__ out) {
    __shared__ __align__(16) uint16_t Bsm[48 * 520];
    int tid = threadIdx.x;
    int l = tid & 63, w = tid >> 6;
    long base = (long)blockIdx.x * 128;
    for (int q = tid; q < 3072; q += 512) {
        int c = q >> 6, k8 = (q & 63) * 8;
        *(uint4*)(Bsm + c * 520 + k8) = *(const uint4*)(w2z + c * 512 + k8);
    }
    if (blockIdx.x == 0 && tid == 0) out[(long)N_NODES * 40] = 0.0f;  // att_loss
    __syncthreads();
    long n0 = base + w * 16 + (l & 15);
    long nld = n0 < N_NODES ? n0 : N_NODES - 1;
    f32x4 acc[3];
    #pragma unroll
    for (int ct = 0; ct < 3; ++ct)
        #pragma unroll
        for (int j = 0; j < 4; ++j) acc[ct][j] = 0.f;
    #pragma unroll
    for (int kb = 0; kb < 16; ++kb) {
        bf16x8 a = *(const bf16x8*)(Zd + nld * 256 + kb * 16 + (l >> 4) * 4);
        #pragma unroll
        for (int ct = 0; ct < 3; ++ct) {
            bf16x8 b = *(const bf16x8*)(Bsm + (ct * 16 + (l & 15)) * 520 + kb * 32 + (l >> 4) * 8);
            acc[ct] = __builtin_amdgcn_mfma_f32_16x16x32_bf16(b, a, acc[ct], 0, 0, 0);
        }
    }
    float v[12];
    int cb0 = (l >> 4) * 4;
    #pragma unroll
    for (int ct = 0; ct < 3; ++ct)
        #pragma unroll
        for (int j = 0; j < 4; ++j) {
            int cb = ct * 16 + cb0 + j;
            v[ct * 4 + j] = (cb < 40) ? acc[ct][j] + b2[cb] : -1e30f;
        }
    float mx = v[0];
    #pragma unroll
    for (int t = 1; t < 12; ++t) mx = fmaxf(mx, v[t]);
    mx = fmaxf(mx, __shfl_xor(mx, 16));
    mx = fmaxf(mx, __shfl_xor(mx, 32));
    float sm = 0.f;
    #pragma unroll
    for (int t = 0; t < 12; ++t) sm += (v[t] > -1e29f) ? __expf(v[t] - mx) : 0.f;
    sm += __shfl_xor(sm, 16);
    sm += __shfl_xor(sm, 32);
    float lse = mx + __logf(sm);
    if (n0 < N_NODES) {
        #pragma unroll
        for (int ct = 0; ct < 3; ++ct)
            #pragma unroll
            for (int j = 0; j < 4; ++j) {
                int cb = ct * 16 + cb0 + j;
                if (cb < 40) out[n0 * 40 + cb] = v[ct * 4 + j] - lse;
            }
    }
}

extern "C" void kernel_launch(void* const* d_in, const int* in_sizes, int n_in,
                              void* d_out, int out_size, void* d_ws, size_t ws_size,
                              hipStream_t stream) {
    const float* x      = (const float*)d_in[0];
    const int*   ei     = (const int*)d_in[1];
    const float* W1     = (const float*)d_in[2];
    const float* att_l1 = (const float*)d_in[3];
    const float* att_r1 = (const float*)d_in[4];
    const float* b1     = (const float*)d_in[5];
    const float* W2     = (const float*)d_in[6];
    const float* att_l2 = (const float*)d_in[7];
    const float* att_r2 = (const float*)d_in[8];
    const float* b2     = (const float*)d_in[9];
    const int* src = ei;
    const int* dst = ei + N_EDGES;
    float* out = (float*)d_out;

    char* ws = (char*)d_ws;
    // Y (102.4 MB) aliases xw1 (25.6) + xw1b (12.8): both dead before ygemm.
    uint16_t* Y      = (uint16_t*)(ws + 0);          // 102.4 MB (later: Z)
    float*    xw1    = (float*)(ws + 0);             // 25.6 MB (dead after conv1)
    uint16_t* xw1b   = (uint16_t*)(ws + 25600000);   // 12.8 MB (dead after conv1)
    uint16_t* hjb    = (uint16_t*)(ws + 102400000);  // 12.8 MB (bf16 h rows)
    float*    al     = (float*)(ws + 115200000);     // 3.2 MB
    float*    ar     = (float*)(ws + 118400000);     // 3.2 MB
    int*      deg    = (int*)(ws + 121600000);       // 400 KB
    int*      offs   = (int*)(ws + 122000000);       // 400 KB
    int*      cursor = (int*)(ws + 122400000);       // 400 KB
    int*      btot   = (int*)(ws + 122800000);       // 1 KB
    int*      csr8   = (int*)(ws + 122801024);       // 6.4 MB
    uint16_t* w1hi   = (uint16_t*)(ws + 129201024);  // 64 KB
    uint16_t* w1lo   = (uint16_t*)(ws + 129266560);  // 64 KB
    uint16_t* mhi    = (uint16_t*)(ws + 129332096);  // 64 KB
    uint16_t* mlo    = (uint16_t*)(ws + 129397632);  // 64 KB
    uint16_t* w2z    = (uint16_t*)(ws + 129463168);  // 48 KB
    float*    wl2    = (float*)(ws + 129512320);     // 2 KB
    float*    wr2    = (float*)(ws + 129514368);     // 2 KB -> ~129.5 MB total

    hipMemsetAsync(deg, 0, (size_t)N_NODES * 4, stream);

    // fused weight prep (blocks: 0-7 cvt_w1 | 8 wvec | 9-56 w2z | 57-64 mcat)
    prep_k<<<65, 512, 0, stream>>>(W1, W2, att_l2, att_r2,
                                   w1hi, w1lo, wl2, wr2, w2z, mhi, mlo);

    // CSR build (dst-sorted adjacency; csr stores src*8)
    hist_k<<<6250, 256, 0, stream>>>(dst, deg);
    scan_a<<<SCAN_NB, 512, 0, stream>>>(deg, offs, btot);
    scan_b<<<1, 256, 0, stream>>>(btot);
    scan_c<<<SCAN_NB, 512, 0, stream>>>(offs, btot, cursor);
    scatter_k<<<6250, 256, 0, stream>>>(src, dst, cursor, csr8);

    // conv1 (al/ar fused into epilogue; hbuf eliminated)
    gemm1_mfma<<<782, 512, 0, stream>>>(x, w1hi, w1lo, xw1, xw1b);
    conv1_node<<<25000, 256, 0, stream>>>(xw1, xw1b, offs, deg, csr8,
                                          att_l1, att_r1, b1, wl2, wr2,
                                          hjb, al, ar);

    // Y = h @ Mcat (after conv1: Y aliases xw1/xw1b)
    ygemm_mfma<<<1564, 512, 0, stream>>>(hjb, mhi, mlo, Y);

    // conv2: h-space attention; writes Z in place over Y
    conv2_node<<<25000, 256, 0, stream>>>(hjb, offs, deg, csr8, al, ar, (uint32_t*)Y);

    // out = Z @ B + b2, fused log_softmax
    zgemm_mfma<<<782, 512, 0, stream>>>((const uint32_t*)Y, w2z, b2, out);
}